// Round 16
// baseline (212.784 us; speedup 1.0000x reference)
//
#include <hip/hip_runtime.h>
#include <cmath>

constexpr int NN   = 100000;
constexpr int NE   = 3200000;
constexpr int DIN  = 128;
constexpr int DH   = 32;
constexpr int DOUT = 20;

constexpr int NB    = 392;                 // coarse buckets: dst>>8 -> 0..390 (+1 pad)
constexpr int NBUSE = (NN + 255) / 256;    // 391 buckets actually used
constexpr int NBLK  = 256;                 // phase A/C blocks
constexpr int SLICE = NE / NBLK;           // 12500 edges per block (exact)

constexpr int NPB = 64;                    // nodes per lin1 block
constexpr int XSB = 136;                   // bf16 LDS row stride (16B-aligned, 2-way banks)
constexpr int PPB = 64;                    // nodes per post block (4 lanes/node)

typedef __attribute__((ext_vector_type(8))) short short8v;   // 8 bf16 (4 VGPRs)
typedef __attribute__((ext_vector_type(4))) float f32x4;     // MFMA accumulator

__device__ inline unsigned short f2bf(float f) {           // RNE float->bf16
    unsigned u = __builtin_bit_cast(unsigned, f);
    unsigned r = 0x7FFFu + ((u >> 16) & 1u);
    return (unsigned short)((u + r) >> 16);
}

// ---- manual fp8 e4m3fn codec (extended-low: e=0 decodes as 2^-7*(1+m/8)) ----
__device__ inline unsigned f2fp8(float f) {                // RNE float->fp8 byte
    unsigned u = __builtin_bit_cast(unsigned, f);
    unsigned s = (u >> 24) & 0x80u;
    unsigned au = u & 0x7fffffffu;
    if (au > 0x43E00000u) au = 0x43E00000u;                // clamp to 448
    unsigned u2 = au + 0x7FFFFu + ((au >> 20) & 1u);       // RNE on dropped 20 bits
    int em = (int)(u2 >> 20) - (120 << 3);                 // (E-120)<<3 | m
    em = em < 0 ? 0 : (em > 0x7E ? 0x7E : em);
    return s | (unsigned)em;
}
__device__ inline float dec8(unsigned b) {                 // fp8 byte -> float
    unsigned r = ((b & 0x80u) << 24) | (((b & 0x7fu) << 20) + 0x3C000000u);
    return __builtin_bit_cast(float, r);
}

// ------------- layer-1 projections via MFMA: xl(fp8)=x@W1l, xr(f32)=x@W1r -------------
__global__ __launch_bounds__(256, 4) void lin1_kernel(
    const float* __restrict__ x, const float* __restrict__ Wl,
    const float* __restrict__ Wr, unsigned char* __restrict__ xlf8,
    float* __restrict__ xr)
{
    __shared__ unsigned short xs[NPB * XSB];   // 17408 B
    int t = threadIdx.x;
    int nodeBase = blockIdx.x * NPB;

    const float4* x4 = reinterpret_cast<const float4*>(x) + (size_t)nodeBase * (DIN / 4);
    for (int i = t; i < NPB * (DIN / 4); i += 256) {
        int n = i >> 5, c = i & 31;
        float4 v = make_float4(0.f, 0.f, 0.f, 0.f);
        if (nodeBase + n < NN) v = x4[i];
        unsigned lo = (unsigned)f2bf(v.x) | ((unsigned)f2bf(v.y) << 16);
        unsigned hi = (unsigned)f2bf(v.z) | ((unsigned)f2bf(v.w) << 16);
        *reinterpret_cast<uint2*>(&xs[n * XSB + c * 4]) = make_uint2(lo, hi);
    }
    __syncthreads();

    int wv   = t >> 6;                 // 0..3
    int lane = t & 63;
    const float* W = (wv & 2) ? Wr : Wl;
    int jbase = (wv & 1) * 16;
    int ncol  = jbase + (lane & 15);   // B: col = lane&15
    int krow  = (lane >> 4) * 8;       // B/A: k-chunk = (lane>>4)*8

    short8v bfrag[4];
#pragma unroll
    for (int ks = 0; ks < 4; ++ks) {
        const float* wp = W + (ks * 32 + krow) * DH + ncol;
        short8v f;
#pragma unroll
        for (int e = 0; e < 8; ++e) f[e] = (short)f2bf(wp[e * DH]);
        bfrag[ks] = f;
    }

    f32x4 acc[4];
#pragma unroll
    for (int m = 0; m < 4; ++m) acc[m] = f32x4{0.f, 0.f, 0.f, 0.f};

#pragma unroll
    for (int m = 0; m < 4; ++m) {
        int row = m * 16 + (lane & 15);
#pragma unroll
        for (int ks = 0; ks < 4; ++ks) {
            short8v a = *reinterpret_cast<const short8v*>(&xs[row * XSB + ks * 32 + krow]);
            acc[m] = __builtin_amdgcn_mfma_f32_16x16x32_bf16(a, bfrag[ks], acc[m], 0, 0, 0);
        }
    }

#pragma unroll
    for (int m = 0; m < 4; ++m) {
        int rbase = m * 16 + (lane >> 4) * 4;
#pragma unroll
        for (int r = 0; r < 4; ++r) {
            int node = nodeBase + rbase + r;
            if (node < NN) {
                float v = acc[m][r];
                if (wv & 2) xr[(size_t)node * DH + ncol] = v;
                else        xlf8[(size_t)node * DH + ncol] = (unsigned char)f2fp8(v);
            }
        }
    }
}

// ---------------- phase A: per-block coarse-bucket histogram (1024 thr) ----------------
__global__ __launch_bounds__(1024) void countA_kernel(
    const int* __restrict__ ei, int* __restrict__ counts)
{
    __shared__ int h[NB];
    int blk = blockIdx.x, t = threadIdx.x;
    for (int i = t; i < NB; i += 1024) h[i] = 0;
    __syncthreads();
    int base = blk * SLICE;
    for (int i = base + t; i < base + SLICE; i += 1024) {
        int dst = ei[NE + i];
        atomicAdd(&h[dst >> 8], 1);
    }
    __syncthreads();
    for (int i = t; i < NB; i += 1024) counts[blk * NB + i] = h[i];
}

// ------- phase B1: per-bucket exclusive scan over 256 block counts -------
__global__ __launch_bounds__(256) void scanB1_kernel(
    const int* __restrict__ counts, int* __restrict__ offs, int* __restrict__ totals)
{
    __shared__ int sdata[256];
    int b = blockIdx.x, t = threadIdx.x;
    int v = counts[t * NB + b];
    sdata[t] = v;
    __syncthreads();
    for (int off = 1; off < 256; off <<= 1) {
        int tmp = (t >= off) ? sdata[t - off] : 0;
        __syncthreads();
        sdata[t] += tmp;
        __syncthreads();
    }
    offs[b * 256 + t] = sdata[t] - v;
    if (t == 255) totals[b] = sdata[255];
}

// ------- phase B2: exclusive scan of bucket totals (tiny) -------
__global__ void scanB2_kernel(const int* __restrict__ totals, int* __restrict__ bases)
{
    if (threadIdx.x == 0 && blockIdx.x == 0) {
        int acc = 0;
        for (int i = 0; i < NB; ++i) { bases[i] = acc; acc += totals[i]; }
        bases[NB] = acc;
    }
}

// ------- phase C: rank-based scatter into per-(block,bucket) regions (1024 thr) -------
__global__ __launch_bounds__(1024) void scatterC_kernel(
    const int* __restrict__ ei, const int* __restrict__ offs,
    const int* __restrict__ bases, unsigned* __restrict__ csrtmp)
{
    __shared__ int cnt[NB];
    __shared__ int wbase[NB];
    int blk = blockIdx.x, t = threadIdx.x;
    for (int i = t; i < NB; i += 1024) {
        cnt[i] = 0;
        wbase[i] = bases[i] + offs[i * 256 + blk];
    }
    __syncthreads();
    int base = blk * SLICE;
    for (int i = base + t; i < base + SLICE; i += 1024) {
        int dst = ei[NE + i];
        int src = ei[i];
        int b = dst >> 8;
        int r = atomicAdd(&cnt[b], 1);                       // LDS atomic
        csrtmp[wbase[b] + r] = ((unsigned)(dst & 255) << 17) | (unsigned)src;
    }
}

// ------- phase D: regroup within bucket -> final CSR + start + deg (1024 thr) -------
__global__ __launch_bounds__(1024) void regroupD_kernel(
    const unsigned* __restrict__ csrtmp, const int* __restrict__ bases,
    int* __restrict__ csrsrc, int* __restrict__ deg, int* __restrict__ start)
{
    __shared__ int h[256];
    __shared__ int sdata[256];
    int b = blockIdx.x, t = threadIdx.x;
    int lo = bases[b], hi = bases[b + 1];
    if (t < 256) h[t] = 0;
    __syncthreads();
    for (int i = lo + t; i < hi; i += 1024)
        atomicAdd(&h[csrtmp[i] >> 17], 1);
    __syncthreads();
    int v = 0;
    if (t < 256) { v = h[t]; sdata[t] = v; }
    __syncthreads();
    for (int off = 1; off < 256; off <<= 1) {
        int tmp = 0;
        if (t < 256 && t >= off) tmp = sdata[t - off];
        __syncthreads();
        if (t < 256) sdata[t] += tmp;
        __syncthreads();
    }
    if (t < 256) {
        int ex = sdata[t] - v;
        int node = b * 256 + t;
        if (node < NN) { start[node] = lo + ex; deg[node] = v; }
        h[t] = ex;
    }
    __syncthreads();
    for (int i = lo + t; i < hi; i += 1024) {
        unsigned u = csrtmp[i];
        int r = atomicAdd(&h[u >> 17], 1);   // LDS atomic
        csrsrc[lo + r] = (int)(u & 0x1FFFFu);
    }
}

// ------- gather (fp8 feat rows, 32 B/row), 8-way unrolled for MLP -------
__global__ __launch_bounds__(256) void gather_kernel(
    const int* __restrict__ start, const int* __restrict__ deg,
    const int* __restrict__ csrsrc, const unsigned* __restrict__ feat8,
    float* __restrict__ agg)
{
    int tid = blockIdx.x * 256 + threadIdx.x;
    int g = tid >> 3;            // node
    int c = tid & 7;             // uint chunk (4 fp8) of the 32-dim row
    if (g >= NN) return;
    int s = start[g];
    int e = s + deg[g];
    float4 a0 = make_float4(0.f, 0.f, 0.f, 0.f);
    float4 a1 = make_float4(0.f, 0.f, 0.f, 0.f);
    float4 a2 = make_float4(0.f, 0.f, 0.f, 0.f);
    float4 a3 = make_float4(0.f, 0.f, 0.f, 0.f);
    int i = s;
    for (; i + 8 <= e; i += 8) {
        int sx[8];
#pragma unroll
        for (int q = 0; q < 8; ++q) sx[q] = csrsrc[i + q];
        unsigned vv[8];
#pragma unroll
        for (int q = 0; q < 8; ++q) vv[q] = feat8[(size_t)sx[q] * 8 + c];
#pragma unroll
        for (int q = 0; q < 2; ++q) {
            unsigned w0 = vv[q * 4 + 0], w1 = vv[q * 4 + 1];
            unsigned w2 = vv[q * 4 + 2], w3 = vv[q * 4 + 3];
            a0.x += dec8(w0 & 0xFFu);         a0.y += dec8((w0 >> 8) & 0xFFu);
            a0.z += dec8((w0 >> 16) & 0xFFu); a0.w += dec8(w0 >> 24);
            a1.x += dec8(w1 & 0xFFu);         a1.y += dec8((w1 >> 8) & 0xFFu);
            a1.z += dec8((w1 >> 16) & 0xFFu); a1.w += dec8(w1 >> 24);
            a2.x += dec8(w2 & 0xFFu);         a2.y += dec8((w2 >> 8) & 0xFFu);
            a2.z += dec8((w2 >> 16) & 0xFFu); a2.w += dec8(w2 >> 24);
            a3.x += dec8(w3 & 0xFFu);         a3.y += dec8((w3 >> 8) & 0xFFu);
            a3.z += dec8((w3 >> 16) & 0xFFu); a3.w += dec8(w3 >> 24);
        }
    }
    for (; i < e; ++i) {
        int s0 = csrsrc[i];
        unsigned w0 = feat8[(size_t)s0 * 8 + c];
        a0.x += dec8(w0 & 0xFFu);         a0.y += dec8((w0 >> 8) & 0xFFu);
        a0.z += dec8((w0 >> 16) & 0xFFu); a0.w += dec8(w0 >> 24);
    }
    a0.x += a1.x + a2.x + a3.x;
    a0.y += a1.y + a2.y + a3.y;
    a0.z += a1.z + a2.z + a3.z;
    a0.w += a1.w + a2.w + a3.w;
    reinterpret_cast<float4*>(agg)[(size_t)g * 8 + c] = a0;
}

// ---- post layer1 (4 lanes/node): o = agg/deg + b1 + xr; h1 = tanh(l2norm(o));
//      hl(fp8) = h1@W2l, hr(f32) = h1@W2r ----
__global__ __launch_bounds__(256) void post1_kernel(
    const float* __restrict__ agg, const int* __restrict__ deg,
    const float* __restrict__ xr, const float* __restrict__ b1,
    const float* __restrict__ W2l, const float* __restrict__ W2r,
    unsigned char* __restrict__ hlf8, float* __restrict__ hr)
{
    __shared__ float hs[PPB][DH + 1];
    int t = threadIdx.x;
    int n = t >> 2;                    // local node 0..63
    int sub = t & 3;                   // dim group: [sub*8, sub*8+8)
    int g = blockIdx.x * PPB + n;
    bool valid = g < NN;

    float o[8];
#pragma unroll
    for (int j = 0; j < 8; ++j) o[j] = 0.f;
    if (valid) {
        float inv = 1.0f / fmaxf((float)deg[g], 1.0f);
        const float4* ag4 = reinterpret_cast<const float4*>(agg + (size_t)g * DH + sub * 8);
        const float4* xr4 = reinterpret_cast<const float4*>(xr  + (size_t)g * DH + sub * 8);
        const float*  bp  = b1 + sub * 8;
#pragma unroll
        for (int q = 0; q < 2; ++q) {
            float4 a = ag4[q]; float4 r = xr4[q];
            o[q*4+0] = fmaf(a.x, inv, bp[q*4+0] + r.x);
            o[q*4+1] = fmaf(a.y, inv, bp[q*4+1] + r.y);
            o[q*4+2] = fmaf(a.z, inv, bp[q*4+2] + r.z);
            o[q*4+3] = fmaf(a.w, inv, bp[q*4+3] + r.w);
        }
    }
    float ss = 0.f;
#pragma unroll
    for (int j = 0; j < 8; ++j) ss += o[j] * o[j];
    ss += __shfl_xor(ss, 1);
    ss += __shfl_xor(ss, 2);
    float rn = 1.0f / fmaxf(sqrtf(ss), 1e-12f);
    float h[8];
#pragma unroll
    for (int j = 0; j < 8; ++j) h[j] = tanhf(o[j] * rn);
#pragma unroll
    for (int j = 0; j < 8; ++j) hs[n][sub * 8 + j] = h[j];
    __syncthreads();

    float al[8], ar[8];
#pragma unroll
    for (int j = 0; j < 8; ++j) { al[j] = 0.f; ar[j] = 0.f; }
    for (int k = 0; k < DH; ++k) {
        float hk = hs[n][k];
        const float4* wl4 = reinterpret_cast<const float4*>(W2l + k * DH + sub * 8);
        const float4* wr4 = reinterpret_cast<const float4*>(W2r + k * DH + sub * 8);
#pragma unroll
        for (int q = 0; q < 2; ++q) {
            float4 wl = wl4[q], wr = wr4[q];
            al[q*4+0] = fmaf(hk, wl.x, al[q*4+0]);
            al[q*4+1] = fmaf(hk, wl.y, al[q*4+1]);
            al[q*4+2] = fmaf(hk, wl.z, al[q*4+2]);
            al[q*4+3] = fmaf(hk, wl.w, al[q*4+3]);
            ar[q*4+0] = fmaf(hk, wr.x, ar[q*4+0]);
            ar[q*4+1] = fmaf(hk, wr.y, ar[q*4+1]);
            ar[q*4+2] = fmaf(hk, wr.z, ar[q*4+2]);
            ar[q*4+3] = fmaf(hk, wr.w, ar[q*4+3]);
        }
    }
    if (valid) {
        unsigned w0 = f2fp8(al[0]) | (f2fp8(al[1]) << 8) |
                      (f2fp8(al[2]) << 16) | (f2fp8(al[3]) << 24);
        unsigned w1 = f2fp8(al[4]) | (f2fp8(al[5]) << 8) |
                      (f2fp8(al[6]) << 16) | (f2fp8(al[7]) << 24);
        *reinterpret_cast<uint2*>(hlf8 + (size_t)g * DH + sub * 8) = make_uint2(w0, w1);
        float4* hr4 = reinterpret_cast<float4*>(hr + (size_t)g * DH + sub * 8);
        hr4[0] = make_float4(ar[0], ar[1], ar[2], ar[3]);
        hr4[1] = make_float4(ar[4], ar[5], ar[6], ar[7]);
    }
}

// ---- post layer2 + classifier (4 lanes/node) ----
__global__ __launch_bounds__(256) void post2_kernel(
    const float* __restrict__ agg, const int* __restrict__ deg,
    const float* __restrict__ hr, const float* __restrict__ b2,
    const float* __restrict__ Wc, const float* __restrict__ bc,
    float* __restrict__ h2out, float* __restrict__ outp)
{
    __shared__ float hs[PPB][DH + 1];
    int t = threadIdx.x;
    int n = t >> 2;
    int sub = t & 3;
    int g = blockIdx.x * PPB + n;
    bool valid = g < NN;

    float o[8];
#pragma unroll
    for (int j = 0; j < 8; ++j) o[j] = 0.f;
    if (valid) {
        float inv = 1.0f / fmaxf((float)deg[g], 1.0f);
        const float4* ag4 = reinterpret_cast<const float4*>(agg + (size_t)g * DH + sub * 8);
        const float4* hr4 = reinterpret_cast<const float4*>(hr  + (size_t)g * DH + sub * 8);
        const float*  bp  = b2 + sub * 8;
#pragma unroll
        for (int q = 0; q < 2; ++q) {
            float4 a = ag4[q]; float4 r = hr4[q];
            o[q*4+0] = fmaf(a.x, inv, bp[q*4+0] + r.x);
            o[q*4+1] = fmaf(a.y, inv, bp[q*4+1] + r.y);
            o[q*4+2] = fmaf(a.z, inv, bp[q*4+2] + r.z);
            o[q*4+3] = fmaf(a.w, inv, bp[q*4+3] + r.w);
        }
    }
    float ss = 0.f;
#pragma unroll
    for (int j = 0; j < 8; ++j) ss += o[j] * o[j];
    ss += __shfl_xor(ss, 1);
    ss += __shfl_xor(ss, 2);
    float rn = 1.0f / fmaxf(sqrtf(ss), 1e-12f);
    float h[8];
#pragma unroll
    for (int j = 0; j < 8; ++j) h[j] = tanhf(o[j] * rn);
#pragma unroll
    for (int j = 0; j < 8; ++j) hs[n][sub * 8 + j] = h[j];
    if (valid) {
        float4* h2o = reinterpret_cast<float4*>(h2out + (size_t)g * DH + sub * 8);
        h2o[0] = make_float4(h[0], h[1], h[2], h[3]);
        h2o[1] = make_float4(h[4], h[5], h[6], h[7]);
    }
    __syncthreads();

    float z[5];
#pragma unroll
    for (int q = 0; q < 5; ++q) z[q] = bc[sub * 5 + q];
    for (int k = 0; k < DH; ++k) {
        float hk = hs[n][k];
        const float* wc = Wc + k * DOUT + sub * 5;
#pragma unroll
        for (int q = 0; q < 5; ++q) z[q] = fmaf(hk, wc[q], z[q]);
    }
    float m = z[0];
#pragma unroll
    for (int q = 1; q < 5; ++q) m = fmaxf(m, z[q]);
    m = fmaxf(m, __shfl_xor(m, 1));
    m = fmaxf(m, __shfl_xor(m, 2));
    float s = 0.f;
#pragma unroll
    for (int q = 0; q < 5; ++q) s += expf(z[q] - m);
    s += __shfl_xor(s, 1);
    s += __shfl_xor(s, 2);
    float lse = m + logf(s);
    if (valid) {
        float* orow = outp + (size_t)g * DOUT + sub * 5;
#pragma unroll
        for (int q = 0; q < 5; ++q) orow[q] = z[q] - lse;
    }
}

extern "C" void kernel_launch(void* const* d_in, const int* in_sizes, int n_in,
                              void* d_out, int out_size, void* d_ws, size_t ws_size,
                              hipStream_t stream) {
    const float* x   = (const float*)d_in[0];
    const int*   ei  = (const int*)d_in[1];
    const float* W1l = (const float*)d_in[2];
    const float* b1  = (const float*)d_in[3];
    const float* W1r = (const float*)d_in[4];
    const float* W2l = (const float*)d_in[5];
    const float* b2  = (const float*)d_in[6];
    const float* W2r = (const float*)d_in[7];
    const float* Wc  = (const float*)d_in[8];
    const float* bc  = (const float*)d_in[9];

    float* outp = (float*)d_out;                          // [NN, 20]
    float* hout = outp + (size_t)NN * DOUT;               // [NN, 32]

    // workspace layout (fp8 feature table: 3.2 MB, L2-resident per XCD)
    unsigned char* xlf8 = (unsigned char*)d_ws;           // NN*DH fp8 (3.2 MB)
    float* xr      = (float*)(xlf8 + (size_t)NN * DH);    // NN*DH f32 (also hr)
    float* agg     = xr + (size_t)NN * DH;                // NN*DH f32 (aliases csrtmp)
    unsigned* csrtmp = (unsigned*)agg;                    // NE u32
    int* csrsrc    = (int*)(agg + (size_t)NN * DH);       // NE
    int* deg       = csrsrc + NE;                         // NN
    int* start     = deg + NN;                            // NN
    int* counts    = start + NN;                          // NBLK*NB
    int* offs      = counts + NBLK * NB;                  // NB*NBLK
    int* totals    = offs + NB * NBLK;                    // NB
    int* bases     = totals + NB;                         // NB+1

    const int lin1Blocks   = (NN + NPB - 1) / NPB;        // 1563
    const int postBlocks   = (NN + PPB - 1) / PPB;        // 1563
    const int gatherBlocks = (NN * 8 + 255) / 256;        // 3125

    lin1_kernel<<<lin1Blocks, 256, 0, stream>>>(x, W1l, W1r, xlf8, xr);

    countA_kernel<<<NBLK, 1024, 0, stream>>>(ei, counts);
    scanB1_kernel<<<NB, 256, 0, stream>>>(counts, offs, totals);
    scanB2_kernel<<<1, 64, 0, stream>>>(totals, bases);
    scatterC_kernel<<<NBLK, 1024, 0, stream>>>(ei, offs, bases, csrtmp);
    regroupD_kernel<<<NBUSE, 1024, 0, stream>>>(csrtmp, bases, csrsrc, deg, start);

    gather_kernel<<<gatherBlocks, 256, 0, stream>>>(start, deg, csrsrc,
                                                    (const unsigned*)xlf8, agg);
    post1_kernel<<<postBlocks, 256, 0, stream>>>(agg, deg, xr, b1, W2l, W2r, xlf8, xr);

    gather_kernel<<<gatherBlocks, 256, 0, stream>>>(start, deg, csrsrc,
                                                    (const unsigned*)xlf8, agg);
    post2_kernel<<<postBlocks, 256, 0, stream>>>(agg, deg, xr, b2, Wc, bc, hout, outp);
}

// Round 17
// 201.086 us; speedup vs baseline: 1.0582x; 1.0582x over previous
//
#include <hip/hip_runtime.h>
#include <cmath>

constexpr int NN   = 100000;
constexpr int NE   = 3200000;
constexpr int DIN  = 128;
constexpr int DH   = 32;
constexpr int DOUT = 20;

constexpr int NB    = 392;                 // coarse buckets: dst>>8 -> 0..390 (+1 pad)
constexpr int NBUSE = (NN + 255) / 256;    // 391 buckets actually used
constexpr int NBLK  = 256;                 // phase A/C blocks
constexpr int SLICE = NE / NBLK;           // 12500 edges per block (exact)

constexpr int NPB = 64;                    // nodes per lin1 block
constexpr int XSB = 136;                   // bf16 LDS row stride (16B-aligned, 2-way banks)
constexpr int PPB = 64;                    // nodes per post block (4 lanes/node)
constexpr int HSS = 36;                    // post hs row stride (16B-aligned, 2-way banks)

typedef __attribute__((ext_vector_type(8))) short short8v;   // 8 bf16 (4 VGPRs)
typedef __attribute__((ext_vector_type(4))) float f32x4;     // MFMA accumulator

__device__ inline unsigned short f2bf(float f) {           // RNE float->bf16
    unsigned u = __builtin_bit_cast(unsigned, f);
    unsigned r = 0x7FFFu + ((u >> 16) & 1u);
    return (unsigned short)((u + r) >> 16);
}

// ---- manual fp8 e4m3fn codec (extended-low: e=0 decodes as 2^-7*(1+m/8)) ----
__device__ inline unsigned f2fp8(float f) {                // RNE float->fp8 byte
    unsigned u = __builtin_bit_cast(unsigned, f);
    unsigned s = (u >> 24) & 0x80u;
    unsigned au = u & 0x7fffffffu;
    if (au > 0x43E00000u) au = 0x43E00000u;                // clamp to 448
    unsigned u2 = au + 0x7FFFFu + ((au >> 20) & 1u);       // RNE on dropped 20 bits
    int em = (int)(u2 >> 20) - (120 << 3);                 // (E-120)<<3 | m
    em = em < 0 ? 0 : (em > 0x7E ? 0x7E : em);
    return s | (unsigned)em;
}
__device__ inline float dec8(unsigned b) {                 // fp8 byte -> float
    unsigned r = ((b & 0x80u) << 24) | (((b & 0x7fu) << 20) + 0x3C000000u);
    return __builtin_bit_cast(float, r);
}

// ------------- layer-1 projections via MFMA: xl(fp8)=x@W1l, xr(f32)=x@W1r -------------
__global__ __launch_bounds__(256, 4) void lin1_kernel(
    const float* __restrict__ x, const float* __restrict__ Wl,
    const float* __restrict__ Wr, unsigned char* __restrict__ xlf8,
    float* __restrict__ xr)
{
    __shared__ unsigned short xs[NPB * XSB];   // 17408 B
    int t = threadIdx.x;
    int nodeBase = blockIdx.x * NPB;

    const float4* x4 = reinterpret_cast<const float4*>(x) + (size_t)nodeBase * (DIN / 4);
    for (int i = t; i < NPB * (DIN / 4); i += 256) {
        int n = i >> 5, c = i & 31;
        float4 v = make_float4(0.f, 0.f, 0.f, 0.f);
        if (nodeBase + n < NN) v = x4[i];
        unsigned lo = (unsigned)f2bf(v.x) | ((unsigned)f2bf(v.y) << 16);
        unsigned hi = (unsigned)f2bf(v.z) | ((unsigned)f2bf(v.w) << 16);
        *reinterpret_cast<uint2*>(&xs[n * XSB + c * 4]) = make_uint2(lo, hi);
    }
    __syncthreads();

    int wv   = t >> 6;                 // 0..3
    int lane = t & 63;
    const float* W = (wv & 2) ? Wr : Wl;
    int jbase = (wv & 1) * 16;
    int ncol  = jbase + (lane & 15);   // B: col = lane&15
    int krow  = (lane >> 4) * 8;       // B/A: k-chunk = (lane>>4)*8

    short8v bfrag[4];
#pragma unroll
    for (int ks = 0; ks < 4; ++ks) {
        const float* wp = W + (ks * 32 + krow) * DH + ncol;
        short8v f;
#pragma unroll
        for (int e = 0; e < 8; ++e) f[e] = (short)f2bf(wp[e * DH]);
        bfrag[ks] = f;
    }

    f32x4 acc[4];
#pragma unroll
    for (int m = 0; m < 4; ++m) acc[m] = f32x4{0.f, 0.f, 0.f, 0.f};

#pragma unroll
    for (int m = 0; m < 4; ++m) {
        int row = m * 16 + (lane & 15);
#pragma unroll
        for (int ks = 0; ks < 4; ++ks) {
            short8v a = *reinterpret_cast<const short8v*>(&xs[row * XSB + ks * 32 + krow]);
            acc[m] = __builtin_amdgcn_mfma_f32_16x16x32_bf16(a, bfrag[ks], acc[m], 0, 0, 0);
        }
    }

#pragma unroll
    for (int m = 0; m < 4; ++m) {
        int rbase = m * 16 + (lane >> 4) * 4;
#pragma unroll
        for (int r = 0; r < 4; ++r) {
            int node = nodeBase + rbase + r;
            if (node < NN) {
                float v = acc[m][r];
                if (wv & 2) xr[(size_t)node * DH + ncol] = v;
                else        xlf8[(size_t)node * DH + ncol] = (unsigned char)f2fp8(v);
            }
        }
    }
}

// ---------------- phase A: per-block coarse-bucket histogram (1024 thr) ----------------
__global__ __launch_bounds__(1024) void countA_kernel(
    const int* __restrict__ ei, int* __restrict__ counts)
{
    __shared__ int h[NB];
    int blk = blockIdx.x, t = threadIdx.x;
    for (int i = t; i < NB; i += 1024) h[i] = 0;
    __syncthreads();
    int base = blk * SLICE;
    for (int i = base + t; i < base + SLICE; i += 1024) {
        int dst = ei[NE + i];
        atomicAdd(&h[dst >> 8], 1);
    }
    __syncthreads();
    for (int i = t; i < NB; i += 1024) counts[blk * NB + i] = h[i];
}

// ------- phase B1: per-bucket exclusive scan over 256 block counts -------
__global__ __launch_bounds__(256) void scanB1_kernel(
    const int* __restrict__ counts, int* __restrict__ offs, int* __restrict__ totals)
{
    __shared__ int sdata[256];
    int b = blockIdx.x, t = threadIdx.x;
    int v = counts[t * NB + b];
    sdata[t] = v;
    __syncthreads();
    for (int off = 1; off < 256; off <<= 1) {
        int tmp = (t >= off) ? sdata[t - off] : 0;
        __syncthreads();
        sdata[t] += tmp;
        __syncthreads();
    }
    offs[b * 256 + t] = sdata[t] - v;
    if (t == 255) totals[b] = sdata[255];
}

// ------- phase B2: exclusive scan of bucket totals (tiny) -------
__global__ void scanB2_kernel(const int* __restrict__ totals, int* __restrict__ bases)
{
    if (threadIdx.x == 0 && blockIdx.x == 0) {
        int acc = 0;
        for (int i = 0; i < NB; ++i) { bases[i] = acc; acc += totals[i]; }
        bases[NB] = acc;
    }
}

// ------- phase C: rank-based scatter into per-(block,bucket) regions (1024 thr) -------
__global__ __launch_bounds__(1024) void scatterC_kernel(
    const int* __restrict__ ei, const int* __restrict__ offs,
    const int* __restrict__ bases, unsigned* __restrict__ csrtmp)
{
    __shared__ int cnt[NB];
    __shared__ int wbase[NB];
    int blk = blockIdx.x, t = threadIdx.x;
    for (int i = t; i < NB; i += 1024) {
        cnt[i] = 0;
        wbase[i] = bases[i] + offs[i * 256 + blk];
    }
    __syncthreads();
    int base = blk * SLICE;
    for (int i = base + t; i < base + SLICE; i += 1024) {
        int dst = ei[NE + i];
        int src = ei[i];
        int b = dst >> 8;
        int r = atomicAdd(&cnt[b], 1);                       // LDS atomic
        csrtmp[wbase[b] + r] = ((unsigned)(dst & 255) << 17) | (unsigned)src;
    }
}

// ------- phase D: regroup within bucket -> final CSR + start + deg (1024 thr) -------
__global__ __launch_bounds__(1024) void regroupD_kernel(
    const unsigned* __restrict__ csrtmp, const int* __restrict__ bases,
    int* __restrict__ csrsrc, int* __restrict__ deg, int* __restrict__ start)
{
    __shared__ int h[256];
    __shared__ int sdata[256];
    int b = blockIdx.x, t = threadIdx.x;
    int lo = bases[b], hi = bases[b + 1];
    if (t < 256) h[t] = 0;
    __syncthreads();
    for (int i = lo + t; i < hi; i += 1024)
        atomicAdd(&h[csrtmp[i] >> 17], 1);
    __syncthreads();
    int v = 0;
    if (t < 256) { v = h[t]; sdata[t] = v; }
    __syncthreads();
    for (int off = 1; off < 256; off <<= 1) {
        int tmp = 0;
        if (t < 256 && t >= off) tmp = sdata[t - off];
        __syncthreads();
        if (t < 256) sdata[t] += tmp;
        __syncthreads();
    }
    if (t < 256) {
        int ex = sdata[t] - v;
        int node = b * 256 + t;
        if (node < NN) { start[node] = lo + ex; deg[node] = v; }
        h[t] = ex;
    }
    __syncthreads();
    for (int i = lo + t; i < hi; i += 1024) {
        unsigned u = csrtmp[i];
        int r = atomicAdd(&h[u >> 17], 1);   // LDS atomic
        csrsrc[lo + r] = (int)(u & 0x1FFFFu);
    }
}

// ------- gather (fp8 feat rows, 32 B/row), 8-way unrolled for MLP -------
__global__ __launch_bounds__(256) void gather_kernel(
    const int* __restrict__ start, const int* __restrict__ deg,
    const int* __restrict__ csrsrc, const unsigned* __restrict__ feat8,
    float* __restrict__ agg)
{
    int tid = blockIdx.x * 256 + threadIdx.x;
    int g = tid >> 3;            // node
    int c = tid & 7;             // uint chunk (4 fp8) of the 32-dim row
    if (g >= NN) return;
    int s = start[g];
    int e = s + deg[g];
    float4 a0 = make_float4(0.f, 0.f, 0.f, 0.f);
    float4 a1 = make_float4(0.f, 0.f, 0.f, 0.f);
    float4 a2 = make_float4(0.f, 0.f, 0.f, 0.f);
    float4 a3 = make_float4(0.f, 0.f, 0.f, 0.f);
    int i = s;
    for (; i + 8 <= e; i += 8) {
        int sx[8];
#pragma unroll
        for (int q = 0; q < 8; ++q) sx[q] = csrsrc[i + q];
        unsigned vv[8];
#pragma unroll
        for (int q = 0; q < 8; ++q) vv[q] = feat8[(size_t)sx[q] * 8 + c];
#pragma unroll
        for (int q = 0; q < 2; ++q) {
            unsigned w0 = vv[q * 4 + 0], w1 = vv[q * 4 + 1];
            unsigned w2 = vv[q * 4 + 2], w3 = vv[q * 4 + 3];
            a0.x += dec8(w0 & 0xFFu);         a0.y += dec8((w0 >> 8) & 0xFFu);
            a0.z += dec8((w0 >> 16) & 0xFFu); a0.w += dec8(w0 >> 24);
            a1.x += dec8(w1 & 0xFFu);         a1.y += dec8((w1 >> 8) & 0xFFu);
            a1.z += dec8((w1 >> 16) & 0xFFu); a1.w += dec8(w1 >> 24);
            a2.x += dec8(w2 & 0xFFu);         a2.y += dec8((w2 >> 8) & 0xFFu);
            a2.z += dec8((w2 >> 16) & 0xFFu); a2.w += dec8(w2 >> 24);
            a3.x += dec8(w3 & 0xFFu);         a3.y += dec8((w3 >> 8) & 0xFFu);
            a3.z += dec8((w3 >> 16) & 0xFFu); a3.w += dec8(w3 >> 24);
        }
    }
    for (; i < e; ++i) {
        int s0 = csrsrc[i];
        unsigned w0 = feat8[(size_t)s0 * 8 + c];
        a0.x += dec8(w0 & 0xFFu);         a0.y += dec8((w0 >> 8) & 0xFFu);
        a0.z += dec8((w0 >> 16) & 0xFFu); a0.w += dec8(w0 >> 24);
    }
    a0.x += a1.x + a2.x + a3.x;
    a0.y += a1.y + a2.y + a3.y;
    a0.z += a1.z + a2.z + a3.z;
    a0.w += a1.w + a2.w + a3.w;
    reinterpret_cast<float4*>(agg)[(size_t)g * 8 + c] = a0;
}

// ---- post layer1 (4 lanes/node): o = agg/deg + b1 + xr; h1 = tanh(l2norm(o));
//      hl(fp8) = h1@W2l, hr(f32) = h1@W2r  — split k-loops, aligned hs ----
__global__ __launch_bounds__(256) void post1_kernel(
    const float* __restrict__ agg, const int* __restrict__ deg,
    const float* __restrict__ xr, const float* __restrict__ b1,
    const float* __restrict__ W2l, const float* __restrict__ W2r,
    unsigned char* __restrict__ hlf8, float* __restrict__ hr)
{
    __shared__ float hs[PPB][HSS];     // stride 36: 16B-aligned rows, 2-way banks
    int t = threadIdx.x;
    int n = t >> 2;                    // local node 0..63
    int sub = t & 3;                   // dim group: [sub*8, sub*8+8)
    int g = blockIdx.x * PPB + n;
    bool valid = g < NN;

    float o[8];
#pragma unroll
    for (int j = 0; j < 8; ++j) o[j] = 0.f;
    if (valid) {
        float inv = 1.0f / fmaxf((float)deg[g], 1.0f);
        const float4* ag4 = reinterpret_cast<const float4*>(agg + (size_t)g * DH + sub * 8);
        const float4* xr4 = reinterpret_cast<const float4*>(xr  + (size_t)g * DH + sub * 8);
        const float*  bp  = b1 + sub * 8;
#pragma unroll
        for (int q = 0; q < 2; ++q) {
            float4 a = ag4[q]; float4 r = xr4[q];
            o[q*4+0] = fmaf(a.x, inv, bp[q*4+0] + r.x);
            o[q*4+1] = fmaf(a.y, inv, bp[q*4+1] + r.y);
            o[q*4+2] = fmaf(a.z, inv, bp[q*4+2] + r.z);
            o[q*4+3] = fmaf(a.w, inv, bp[q*4+3] + r.w);
        }
    }
    float ss = 0.f;
#pragma unroll
    for (int j = 0; j < 8; ++j) ss += o[j] * o[j];
    ss += __shfl_xor(ss, 1);
    ss += __shfl_xor(ss, 2);
    float rn = 1.0f / fmaxf(sqrtf(ss), 1e-12f);
#pragma unroll
    for (int j = 0; j < 8; ++j) hs[n][sub * 8 + j] = tanhf(o[j] * rn);
    __syncthreads();

    // ---- loop A: al = h @ W2l (8 cols), fp8 encode + store ----
    float al[8];
#pragma unroll
    for (int j = 0; j < 8; ++j) al[j] = 0.f;
#pragma unroll
    for (int k4 = 0; k4 < 8; ++k4) {
        float4 hv = *reinterpret_cast<const float4*>(&hs[n][k4 * 4]);   // ds_read_b128
        float hk[4] = {hv.x, hv.y, hv.z, hv.w};
#pragma unroll
        for (int kk = 0; kk < 4; ++kk) {
            const float4* wl4 = reinterpret_cast<const float4*>(W2l + (k4*4+kk) * DH + sub * 8);
            float4 w0 = wl4[0], w1 = wl4[1];
            al[0] = fmaf(hk[kk], w0.x, al[0]);
            al[1] = fmaf(hk[kk], w0.y, al[1]);
            al[2] = fmaf(hk[kk], w0.z, al[2]);
            al[3] = fmaf(hk[kk], w0.w, al[3]);
            al[4] = fmaf(hk[kk], w1.x, al[4]);
            al[5] = fmaf(hk[kk], w1.y, al[5]);
            al[6] = fmaf(hk[kk], w1.z, al[6]);
            al[7] = fmaf(hk[kk], w1.w, al[7]);
        }
    }
    if (valid) {
        unsigned w0 = f2fp8(al[0]) | (f2fp8(al[1]) << 8) |
                      (f2fp8(al[2]) << 16) | (f2fp8(al[3]) << 24);
        unsigned w1 = f2fp8(al[4]) | (f2fp8(al[5]) << 8) |
                      (f2fp8(al[6]) << 16) | (f2fp8(al[7]) << 24);
        *reinterpret_cast<uint2*>(hlf8 + (size_t)g * DH + sub * 8) = make_uint2(w0, w1);
    }

    // ---- loop B: ar = h @ W2r (8 cols), f32 store ----
    float ar[8];
#pragma unroll
    for (int j = 0; j < 8; ++j) ar[j] = 0.f;
#pragma unroll
    for (int k4 = 0; k4 < 8; ++k4) {
        float4 hv = *reinterpret_cast<const float4*>(&hs[n][k4 * 4]);
        float hk[4] = {hv.x, hv.y, hv.z, hv.w};
#pragma unroll
        for (int kk = 0; kk < 4; ++kk) {
            const float4* wr4 = reinterpret_cast<const float4*>(W2r + (k4*4+kk) * DH + sub * 8);
            float4 w0 = wr4[0], w1 = wr4[1];
            ar[0] = fmaf(hk[kk], w0.x, ar[0]);
            ar[1] = fmaf(hk[kk], w0.y, ar[1]);
            ar[2] = fmaf(hk[kk], w0.z, ar[2]);
            ar[3] = fmaf(hk[kk], w0.w, ar[3]);
            ar[4] = fmaf(hk[kk], w1.x, ar[4]);
            ar[5] = fmaf(hk[kk], w1.y, ar[5]);
            ar[6] = fmaf(hk[kk], w1.z, ar[6]);
            ar[7] = fmaf(hk[kk], w1.w, ar[7]);
        }
    }
    if (valid) {
        float4* hr4 = reinterpret_cast<float4*>(hr + (size_t)g * DH + sub * 8);
        hr4[0] = make_float4(ar[0], ar[1], ar[2], ar[3]);
        hr4[1] = make_float4(ar[4], ar[5], ar[6], ar[7]);
    }
}

// ---- post layer2 + classifier (4 lanes/node), aligned hs ----
__global__ __launch_bounds__(256) void post2_kernel(
    const float* __restrict__ agg, const int* __restrict__ deg,
    const float* __restrict__ hr, const float* __restrict__ b2,
    const float* __restrict__ Wc, const float* __restrict__ bc,
    float* __restrict__ h2out, float* __restrict__ outp)
{
    __shared__ float hs[PPB][HSS];
    int t = threadIdx.x;
    int n = t >> 2;
    int sub = t & 3;
    int g = blockIdx.x * PPB + n;
    bool valid = g < NN;

    float o[8];
#pragma unroll
    for (int j = 0; j < 8; ++j) o[j] = 0.f;
    if (valid) {
        float inv = 1.0f / fmaxf((float)deg[g], 1.0f);
        const float4* ag4 = reinterpret_cast<const float4*>(agg + (size_t)g * DH + sub * 8);
        const float4* hr4 = reinterpret_cast<const float4*>(hr  + (size_t)g * DH + sub * 8);
        const float*  bp  = b2 + sub * 8;
#pragma unroll
        for (int q = 0; q < 2; ++q) {
            float4 a = ag4[q]; float4 r = hr4[q];
            o[q*4+0] = fmaf(a.x, inv, bp[q*4+0] + r.x);
            o[q*4+1] = fmaf(a.y, inv, bp[q*4+1] + r.y);
            o[q*4+2] = fmaf(a.z, inv, bp[q*4+2] + r.z);
            o[q*4+3] = fmaf(a.w, inv, bp[q*4+3] + r.w);
        }
    }
    float ss = 0.f;
#pragma unroll
    for (int j = 0; j < 8; ++j) ss += o[j] * o[j];
    ss += __shfl_xor(ss, 1);
    ss += __shfl_xor(ss, 2);
    float rn = 1.0f / fmaxf(sqrtf(ss), 1e-12f);
    float h[8];
#pragma unroll
    for (int j = 0; j < 8; ++j) h[j] = tanhf(o[j] * rn);
#pragma unroll
    for (int j = 0; j < 8; ++j) hs[n][sub * 8 + j] = h[j];
    if (valid) {
        float4* h2o = reinterpret_cast<float4*>(h2out + (size_t)g * DH + sub * 8);
        h2o[0] = make_float4(h[0], h[1], h[2], h[3]);
        h2o[1] = make_float4(h[4], h[5], h[6], h[7]);
    }
    __syncthreads();

    float z[5];
#pragma unroll
    for (int q = 0; q < 5; ++q) z[q] = bc[sub * 5 + q];
#pragma unroll
    for (int k4 = 0; k4 < 8; ++k4) {
        float4 hv = *reinterpret_cast<const float4*>(&hs[n][k4 * 4]);   // ds_read_b128
        float hk[4] = {hv.x, hv.y, hv.z, hv.w};
#pragma unroll
        for (int kk = 0; kk < 4; ++kk) {
            const float* wc = Wc + (k4*4+kk) * DOUT + sub * 5;
#pragma unroll
            for (int q = 0; q < 5; ++q) z[q] = fmaf(hk[kk], wc[q], z[q]);
        }
    }
    float m = z[0];
#pragma unroll
    for (int q = 1; q < 5; ++q) m = fmaxf(m, z[q]);
    m = fmaxf(m, __shfl_xor(m, 1));
    m = fmaxf(m, __shfl_xor(m, 2));
    float s = 0.f;
#pragma unroll
    for (int q = 0; q < 5; ++q) s += expf(z[q] - m);
    s += __shfl_xor(s, 1);
    s += __shfl_xor(s, 2);
    float lse = m + logf(s);
    if (valid) {
        float* orow = outp + (size_t)g * DOUT + sub * 5;
#pragma unroll
        for (int q = 0; q < 5; ++q) orow[q] = z[q] - lse;
    }
}

extern "C" void kernel_launch(void* const* d_in, const int* in_sizes, int n_in,
                              void* d_out, int out_size, void* d_ws, size_t ws_size,
                              hipStream_t stream) {
    const float* x   = (const float*)d_in[0];
    const int*   ei  = (const int*)d_in[1];
    const float* W1l = (const float*)d_in[2];
    const float* b1  = (const float*)d_in[3];
    const float* W1r = (const float*)d_in[4];
    const float* W2l = (const float*)d_in[5];
    const float* b2  = (const float*)d_in[6];
    const float* W2r = (const float*)d_in[7];
    const float* Wc  = (const float*)d_in[8];
    const float* bc  = (const float*)d_in[9];

    float* outp = (float*)d_out;                          // [NN, 20]
    float* hout = outp + (size_t)NN * DOUT;               // [NN, 32]

    // workspace layout (fp8 feature table: 3.2 MB, L2-resident per XCD)
    unsigned char* xlf8 = (unsigned char*)d_ws;           // NN*DH fp8 (3.2 MB)
    float* xr      = (float*)(xlf8 + (size_t)NN * DH);    // NN*DH f32 (also hr)
    float* agg     = xr + (size_t)NN * DH;                // NN*DH f32 (aliases csrtmp)
    unsigned* csrtmp = (unsigned*)agg;                    // NE u32
    int* csrsrc    = (int*)(agg + (size_t)NN * DH);       // NE
    int* deg       = csrsrc + NE;                         // NN
    int* start     = deg + NN;                            // NN
    int* counts    = start + NN;                          // NBLK*NB
    int* offs      = counts + NBLK * NB;                  // NB*NBLK
    int* totals    = offs + NB * NBLK;                    // NB
    int* bases     = totals + NB;                         // NB+1

    const int lin1Blocks   = (NN + NPB - 1) / NPB;        // 1563
    const int postBlocks   = (NN + PPB - 1) / PPB;        // 1563
    const int gatherBlocks = (NN * 8 + 255) / 256;        // 3125

    lin1_kernel<<<lin1Blocks, 256, 0, stream>>>(x, W1l, W1r, xlf8, xr);

    countA_kernel<<<NBLK, 1024, 0, stream>>>(ei, counts);
    scanB1_kernel<<<NB, 256, 0, stream>>>(counts, offs, totals);
    scanB2_kernel<<<1, 64, 0, stream>>>(totals, bases);
    scatterC_kernel<<<NBLK, 1024, 0, stream>>>(ei, offs, bases, csrtmp);
    regroupD_kernel<<<NBUSE, 1024, 0, stream>>>(csrtmp, bases, csrsrc, deg, start);

    gather_kernel<<<gatherBlocks, 256, 0, stream>>>(start, deg, csrsrc,
                                                    (const unsigned*)xlf8, agg);
    post1_kernel<<<postBlocks, 256, 0, stream>>>(agg, deg, xr, b1, W2l, W2r, xlf8, xr);

    gather_kernel<<<gatherBlocks, 256, 0, stream>>>(start, deg, csrsrc,
                                                    (const unsigned*)xlf8, agg);
    post2_kernel<<<postBlocks, 256, 0, stream>>>(agg, deg, xr, b2, Wc, bc, hout, outp);
}

// Round 18
// 190.618 us; speedup vs baseline: 1.1163x; 1.0549x over previous
//
#include <hip/hip_runtime.h>
#include <hip/hip_fp16.h>
#include <cmath>

constexpr int NN   = 100000;
constexpr int NE   = 3200000;
constexpr int DIN  = 128;
constexpr int DH   = 32;
constexpr int DOUT = 20;

constexpr int NB    = 392;                 // coarse buckets: dst>>8 -> 0..390 (+1 pad)
constexpr int NBUSE = (NN + 255) / 256;    // 391 buckets actually used
constexpr int NBLK  = 256;                 // phase A/C blocks
constexpr int SLICE = NE / NBLK;           // 12500 edges per block (exact)

constexpr int NPB = 64;                    // nodes per lin1 block
constexpr int XSB = 136;                   // bf16 LDS row stride (16B-aligned, 2-way banks)
constexpr int PPB = 64;                    // nodes per post block (4 lanes/node)
constexpr int HSS = 36;                    // post hs row stride (16B-aligned, 2-way banks)

typedef __attribute__((ext_vector_type(8))) short short8v;   // 8 bf16 (4 VGPRs)
typedef __attribute__((ext_vector_type(4))) float f32x4;     // MFMA accumulator

__device__ inline unsigned short f2bf(float f) {           // RNE float->bf16
    unsigned u = __builtin_bit_cast(unsigned, f);
    unsigned r = 0x7FFFu + ((u >> 16) & 1u);
    return (unsigned short)((u + r) >> 16);
}

// ---- manual fp8 e4m3fn codec (extended-low: e=0 decodes as 2^-7*(1+m/8)) ----
__device__ inline unsigned f2fp8(float f) {                // RNE float->fp8 byte
    unsigned u = __builtin_bit_cast(unsigned, f);
    unsigned s = (u >> 24) & 0x80u;
    unsigned au = u & 0x7fffffffu;
    if (au > 0x43E00000u) au = 0x43E00000u;                // clamp to 448
    unsigned u2 = au + 0x7FFFFu + ((au >> 20) & 1u);       // RNE on dropped 20 bits
    int em = (int)(u2 >> 20) - (120 << 3);                 // (E-120)<<3 | m
    em = em < 0 ? 0 : (em > 0x7E ? 0x7E : em);
    return s | (unsigned)em;
}
__device__ inline float dec8(unsigned b) {                 // fp8 byte -> float
    unsigned r = ((b & 0x80u) << 24) | (((b & 0x7fu) << 20) + 0x3C000000u);
    return __builtin_bit_cast(float, r);
}

// ------------- layer-1 projections via MFMA: xl(fp8)=x@W1l, xr(f32)=x@W1r -------------
__global__ __launch_bounds__(256, 4) void lin1_kernel(
    const float* __restrict__ x, const float* __restrict__ Wl,
    const float* __restrict__ Wr, unsigned char* __restrict__ xlf8,
    float* __restrict__ xr)
{
    __shared__ unsigned short xs[NPB * XSB];   // 17408 B
    int t = threadIdx.x;
    int nodeBase = blockIdx.x * NPB;

    const float4* x4 = reinterpret_cast<const float4*>(x) + (size_t)nodeBase * (DIN / 4);
    for (int i = t; i < NPB * (DIN / 4); i += 256) {
        int n = i >> 5, c = i & 31;
        float4 v = make_float4(0.f, 0.f, 0.f, 0.f);
        if (nodeBase + n < NN) v = x4[i];
        unsigned lo = (unsigned)f2bf(v.x) | ((unsigned)f2bf(v.y) << 16);
        unsigned hi = (unsigned)f2bf(v.z) | ((unsigned)f2bf(v.w) << 16);
        *reinterpret_cast<uint2*>(&xs[n * XSB + c * 4]) = make_uint2(lo, hi);
    }
    __syncthreads();

    int wv   = t >> 6;                 // 0..3
    int lane = t & 63;
    const float* W = (wv & 2) ? Wr : Wl;
    int jbase = (wv & 1) * 16;
    int ncol  = jbase + (lane & 15);   // B: col = lane&15
    int krow  = (lane >> 4) * 8;       // B/A: k-chunk = (lane>>4)*8

    short8v bfrag[4];
#pragma unroll
    for (int ks = 0; ks < 4; ++ks) {
        const float* wp = W + (ks * 32 + krow) * DH + ncol;
        short8v f;
#pragma unroll
        for (int e = 0; e < 8; ++e) f[e] = (short)f2bf(wp[e * DH]);
        bfrag[ks] = f;
    }

    f32x4 acc[4];
#pragma unroll
    for (int m = 0; m < 4; ++m) acc[m] = f32x4{0.f, 0.f, 0.f, 0.f};

#pragma unroll
    for (int m = 0; m < 4; ++m) {
        int row = m * 16 + (lane & 15);
#pragma unroll
        for (int ks = 0; ks < 4; ++ks) {
            short8v a = *reinterpret_cast<const short8v*>(&xs[row * XSB + ks * 32 + krow]);
            acc[m] = __builtin_amdgcn_mfma_f32_16x16x32_bf16(a, bfrag[ks], acc[m], 0, 0, 0);
        }
    }

#pragma unroll
    for (int m = 0; m < 4; ++m) {
        int rbase = m * 16 + (lane >> 4) * 4;
#pragma unroll
        for (int r = 0; r < 4; ++r) {
            int node = nodeBase + rbase + r;
            if (node < NN) {
                float v = acc[m][r];
                if (wv & 2) xr[(size_t)node * DH + ncol] = v;
                else        xlf8[(size_t)node * DH + ncol] = (unsigned char)f2fp8(v);
            }
        }
    }
}

// ---------------- phase A: per-block coarse-bucket histogram (1024 thr) ----------------
__global__ __launch_bounds__(1024) void countA_kernel(
    const int* __restrict__ ei, int* __restrict__ counts)
{
    __shared__ int h[NB];
    int blk = blockIdx.x, t = threadIdx.x;
    for (int i = t; i < NB; i += 1024) h[i] = 0;
    __syncthreads();
    int base = blk * SLICE;
    for (int i = base + t; i < base + SLICE; i += 1024) {
        int dst = ei[NE + i];
        atomicAdd(&h[dst >> 8], 1);
    }
    __syncthreads();
    for (int i = t; i < NB; i += 1024) counts[blk * NB + i] = h[i];
}

// ------- phase B1: per-bucket exclusive scan over 256 block counts -------
__global__ __launch_bounds__(256) void scanB1_kernel(
    const int* __restrict__ counts, int* __restrict__ offs, int* __restrict__ totals)
{
    __shared__ int sdata[256];
    int b = blockIdx.x, t = threadIdx.x;
    int v = counts[t * NB + b];
    sdata[t] = v;
    __syncthreads();
    for (int off = 1; off < 256; off <<= 1) {
        int tmp = (t >= off) ? sdata[t - off] : 0;
        __syncthreads();
        sdata[t] += tmp;
        __syncthreads();
    }
    offs[b * 256 + t] = sdata[t] - v;
    if (t == 255) totals[b] = sdata[255];
}

// ------- phase B2: exclusive scan of bucket totals (tiny) -------
__global__ void scanB2_kernel(const int* __restrict__ totals, int* __restrict__ bases)
{
    if (threadIdx.x == 0 && blockIdx.x == 0) {
        int acc = 0;
        for (int i = 0; i < NB; ++i) { bases[i] = acc; acc += totals[i]; }
        bases[NB] = acc;
    }
}

// ------- phase C: rank-based scatter into per-(block,bucket) regions (1024 thr) -------
__global__ __launch_bounds__(1024) void scatterC_kernel(
    const int* __restrict__ ei, const int* __restrict__ offs,
    const int* __restrict__ bases, unsigned* __restrict__ csrtmp)
{
    __shared__ int cnt[NB];
    __shared__ int wbase[NB];
    int blk = blockIdx.x, t = threadIdx.x;
    for (int i = t; i < NB; i += 1024) {
        cnt[i] = 0;
        wbase[i] = bases[i] + offs[i * 256 + blk];
    }
    __syncthreads();
    int base = blk * SLICE;
    for (int i = base + t; i < base + SLICE; i += 1024) {
        int dst = ei[NE + i];
        int src = ei[i];
        int b = dst >> 8;
        int r = atomicAdd(&cnt[b], 1);                       // LDS atomic
        csrtmp[wbase[b] + r] = ((unsigned)(dst & 255) << 17) | (unsigned)src;
    }
}

// ------- phase D: regroup within bucket -> final CSR + start + deg (1024 thr) -------
__global__ __launch_bounds__(1024) void regroupD_kernel(
    const unsigned* __restrict__ csrtmp, const int* __restrict__ bases,
    int* __restrict__ csrsrc, int* __restrict__ deg, int* __restrict__ start)
{
    __shared__ int h[256];
    __shared__ int sdata[256];
    int b = blockIdx.x, t = threadIdx.x;
    int lo = bases[b], hi = bases[b + 1];
    if (t < 256) h[t] = 0;
    __syncthreads();
    for (int i = lo + t; i < hi; i += 1024)
        atomicAdd(&h[csrtmp[i] >> 17], 1);
    __syncthreads();
    int v = 0;
    if (t < 256) { v = h[t]; sdata[t] = v; }
    __syncthreads();
    for (int off = 1; off < 256; off <<= 1) {
        int tmp = 0;
        if (t < 256 && t >= off) tmp = sdata[t - off];
        __syncthreads();
        if (t < 256) sdata[t] += tmp;
        __syncthreads();
    }
    if (t < 256) {
        int ex = sdata[t] - v;
        int node = b * 256 + t;
        if (node < NN) { start[node] = lo + ex; deg[node] = v; }
        h[t] = ex;
    }
    __syncthreads();
    for (int i = lo + t; i < hi; i += 1024) {
        unsigned u = csrtmp[i];
        int r = atomicAdd(&h[u >> 17], 1);   // LDS atomic
        csrsrc[lo + r] = (int)(u & 0x1FFFFu);
    }
}

// ------- gather (fp8 rows, 32 B/row): packed-f16 accumulate, 32-bit addressing -------
__global__ __launch_bounds__(256) void gather_kernel(
    const int* __restrict__ start, const int* __restrict__ deg,
    const int* __restrict__ csrsrc, const unsigned* __restrict__ feat8,
    float* __restrict__ agg)
{
    int tid = blockIdx.x * 256 + threadIdx.x;
    int g = tid >> 3;            // node
    unsigned c = tid & 7;        // uint chunk (4 fp8) of the 32-dim row
    if (g >= NN) return;
    int s = start[g];
    int e = s + deg[g];
    __half2 zero2 = __float2half2_rn(0.f);
    __half2 p0a = zero2, p0b = zero2, p1a = zero2, p1b = zero2;
    __half2 p2a = zero2, p2b = zero2, p3a = zero2, p3b = zero2;
    int i = s;
    for (; i + 8 <= e; i += 8) {
        unsigned off[8];
#pragma unroll
        for (int q = 0; q < 8; ++q) off[q] = (unsigned)csrsrc[i + q] * 8u + c;
        unsigned vv[8];
#pragma unroll
        for (int q = 0; q < 8; ++q) vv[q] = feat8[off[q]];
#pragma unroll
        for (int q = 0; q < 8; ++q) {
            unsigned w = vv[q];
            unsigned p01 = __builtin_amdgcn_perm(0u, w, 0x04010400u); // 0x00b1_00b0
            unsigned p23 = __builtin_amdgcn_perm(0u, w, 0x04030402u); // 0x00b3_00b2
            unsigned h01 = ((p01 & 0x00800080u) << 8) |
                           (((p01 << 7) & 0x3F803F80u) + 0x20002000u); // fp8->f16 exact
            unsigned h23 = ((p23 & 0x00800080u) << 8) |
                           (((p23 << 7) & 0x3F803F80u) + 0x20002000u);
            __half2 a01 = __builtin_bit_cast(__half2, h01);
            __half2 a23 = __builtin_bit_cast(__half2, h23);
            if ((q & 3) == 0) { p0a = __hadd2(p0a, a01); p0b = __hadd2(p0b, a23); }
            if ((q & 3) == 1) { p1a = __hadd2(p1a, a01); p1b = __hadd2(p1b, a23); }
            if ((q & 3) == 2) { p2a = __hadd2(p2a, a01); p2b = __hadd2(p2b, a23); }
            if ((q & 3) == 3) { p3a = __hadd2(p3a, a01); p3b = __hadd2(p3b, a23); }
        }
    }
    float4 tl = make_float4(0.f, 0.f, 0.f, 0.f);
    for (; i < e; ++i) {
        unsigned w = feat8[(unsigned)csrsrc[i] * 8u + c];
        tl.x += dec8(w & 0xFFu);         tl.y += dec8((w >> 8) & 0xFFu);
        tl.z += dec8((w >> 16) & 0xFFu); tl.w += dec8(w >> 24);
    }
    float2 f0a = __half22float2(p0a), f1a = __half22float2(p1a);
    float2 f2a = __half22float2(p2a), f3a = __half22float2(p3a);
    float2 f0b = __half22float2(p0b), f1b = __half22float2(p1b);
    float2 f2b = __half22float2(p2b), f3b = __half22float2(p3b);
    float4 r;
    r.x = tl.x + f0a.x + f1a.x + f2a.x + f3a.x;
    r.y = tl.y + f0a.y + f1a.y + f2a.y + f3a.y;
    r.z = tl.z + f0b.x + f1b.x + f2b.x + f3b.x;
    r.w = tl.w + f0b.y + f1b.y + f2b.y + f3b.y;
    reinterpret_cast<float4*>(agg)[(size_t)g * 8 + c] = r;
}

// ---- post layer1 (4 lanes/node): o = agg/deg + b1 + xr; h1 = tanh(l2norm(o));
//      hl(fp8) = h1@W2l, hr(f32) = h1@W2r  — split k-loops, aligned hs ----
__global__ __launch_bounds__(256) void post1_kernel(
    const float* __restrict__ agg, const int* __restrict__ deg,
    const float* __restrict__ xr, const float* __restrict__ b1,
    const float* __restrict__ W2l, const float* __restrict__ W2r,
    unsigned char* __restrict__ hlf8, float* __restrict__ hr)
{
    __shared__ float hs[PPB][HSS];     // stride 36: 16B-aligned rows, 2-way banks
    int t = threadIdx.x;
    int n = t >> 2;                    // local node 0..63
    int sub = t & 3;                   // dim group: [sub*8, sub*8+8)
    int g = blockIdx.x * PPB + n;
    bool valid = g < NN;

    float o[8];
#pragma unroll
    for (int j = 0; j < 8; ++j) o[j] = 0.f;
    if (valid) {
        float inv = 1.0f / fmaxf((float)deg[g], 1.0f);
        const float4* ag4 = reinterpret_cast<const float4*>(agg + (size_t)g * DH + sub * 8);
        const float4* xr4 = reinterpret_cast<const float4*>(xr  + (size_t)g * DH + sub * 8);
        const float*  bp  = b1 + sub * 8;
#pragma unroll
        for (int q = 0; q < 2; ++q) {
            float4 a = ag4[q]; float4 r = xr4[q];
            o[q*4+0] = fmaf(a.x, inv, bp[q*4+0] + r.x);
            o[q*4+1] = fmaf(a.y, inv, bp[q*4+1] + r.y);
            o[q*4+2] = fmaf(a.z, inv, bp[q*4+2] + r.z);
            o[q*4+3] = fmaf(a.w, inv, bp[q*4+3] + r.w);
        }
    }
    float ss = 0.f;
#pragma unroll
    for (int j = 0; j < 8; ++j) ss += o[j] * o[j];
    ss += __shfl_xor(ss, 1);
    ss += __shfl_xor(ss, 2);
    float rn = 1.0f / fmaxf(sqrtf(ss), 1e-12f);
#pragma unroll
    for (int j = 0; j < 8; ++j) hs[n][sub * 8 + j] = tanhf(o[j] * rn);
    __syncthreads();

    // ---- loop A: al = h @ W2l (8 cols), fp8 encode + store ----
    float al[8];
#pragma unroll
    for (int j = 0; j < 8; ++j) al[j] = 0.f;
#pragma unroll
    for (int k4 = 0; k4 < 8; ++k4) {
        float4 hv = *reinterpret_cast<const float4*>(&hs[n][k4 * 4]);   // ds_read_b128
        float hk[4] = {hv.x, hv.y, hv.z, hv.w};
#pragma unroll
        for (int kk = 0; kk < 4; ++kk) {
            const float4* wl4 = reinterpret_cast<const float4*>(W2l + (k4*4+kk) * DH + sub * 8);
            float4 w0 = wl4[0], w1 = wl4[1];
            al[0] = fmaf(hk[kk], w0.x, al[0]);
            al[1] = fmaf(hk[kk], w0.y, al[1]);
            al[2] = fmaf(hk[kk], w0.z, al[2]);
            al[3] = fmaf(hk[kk], w0.w, al[3]);
            al[4] = fmaf(hk[kk], w1.x, al[4]);
            al[5] = fmaf(hk[kk], w1.y, al[5]);
            al[6] = fmaf(hk[kk], w1.z, al[6]);
            al[7] = fmaf(hk[kk], w1.w, al[7]);
        }
    }
    if (valid) {
        unsigned w0 = f2fp8(al[0]) | (f2fp8(al[1]) << 8) |
                      (f2fp8(al[2]) << 16) | (f2fp8(al[3]) << 24);
        unsigned w1 = f2fp8(al[4]) | (f2fp8(al[5]) << 8) |
                      (f2fp8(al[6]) << 16) | (f2fp8(al[7]) << 24);
        *reinterpret_cast<uint2*>(hlf8 + (size_t)g * DH + sub * 8) = make_uint2(w0, w1);
    }

    // ---- loop B: ar = h @ W2r (8 cols), f32 store ----
    float ar[8];
#pragma unroll
    for (int j = 0; j < 8; ++j) ar[j] = 0.f;
#pragma unroll
    for (int k4 = 0; k4 < 8; ++k4) {
        float4 hv = *reinterpret_cast<const float4*>(&hs[n][k4 * 4]);
        float hk[4] = {hv.x, hv.y, hv.z, hv.w};
#pragma unroll
        for (int kk = 0; kk < 4; ++kk) {
            const float4* wr4 = reinterpret_cast<const float4*>(W2r + (k4*4+kk) * DH + sub * 8);
            float4 w0 = wr4[0], w1 = wr4[1];
            ar[0] = fmaf(hk[kk], w0.x, ar[0]);
            ar[1] = fmaf(hk[kk], w0.y, ar[1]);
            ar[2] = fmaf(hk[kk], w0.z, ar[2]);
            ar[3] = fmaf(hk[kk], w0.w, ar[3]);
            ar[4] = fmaf(hk[kk], w1.x, ar[4]);
            ar[5] = fmaf(hk[kk], w1.y, ar[5]);
            ar[6] = fmaf(hk[kk], w1.z, ar[6]);
            ar[7] = fmaf(hk[kk], w1.w, ar[7]);
        }
    }
    if (valid) {
        float4* hr4 = reinterpret_cast<float4*>(hr + (size_t)g * DH + sub * 8);
        hr4[0] = make_float4(ar[0], ar[1], ar[2], ar[3]);
        hr4[1] = make_float4(ar[4], ar[5], ar[6], ar[7]);
    }
}

// ---- post layer2 + classifier (4 lanes/node), aligned hs ----
__global__ __launch_bounds__(256) void post2_kernel(
    const float* __restrict__ agg, const int* __restrict__ deg,
    const float* __restrict__ hr, const float* __restrict__ b2,
    const float* __restrict__ Wc, const float* __restrict__ bc,
    float* __restrict__ h2out, float* __restrict__ outp)
{
    __shared__ float hs[PPB][HSS];
    int t = threadIdx.x;
    int n = t >> 2;
    int sub = t & 3;
    int g = blockIdx.x * PPB + n;
    bool valid = g < NN;

    float o[8];
#pragma unroll
    for (int j = 0; j < 8; ++j) o[j] = 0.f;
    if (valid) {
        float inv = 1.0f / fmaxf((float)deg[g], 1.0f);
        const float4* ag4 = reinterpret_cast<const float4*>(agg + (size_t)g * DH + sub * 8);
        const float4* hr4 = reinterpret_cast<const float4*>(hr  + (size_t)g * DH + sub * 8);
        const float*  bp  = b2 + sub * 8;
#pragma unroll
        for (int q = 0; q < 2; ++q) {
            float4 a = ag4[q]; float4 r = hr4[q];
            o[q*4+0] = fmaf(a.x, inv, bp[q*4+0] + r.x);
            o[q*4+1] = fmaf(a.y, inv, bp[q*4+1] + r.y);
            o[q*4+2] = fmaf(a.z, inv, bp[q*4+2] + r.z);
            o[q*4+3] = fmaf(a.w, inv, bp[q*4+3] + r.w);
        }
    }
    float ss = 0.f;
#pragma unroll
    for (int j = 0; j < 8; ++j) ss += o[j] * o[j];
    ss += __shfl_xor(ss, 1);
    ss += __shfl_xor(ss, 2);
    float rn = 1.0f / fmaxf(sqrtf(ss), 1e-12f);
    float h[8];
#pragma unroll
    for (int j = 0; j < 8; ++j) h[j] = tanhf(o[j] * rn);
#pragma unroll
    for (int j = 0; j < 8; ++j) hs[n][sub * 8 + j] = h[j];
    if (valid) {
        float4* h2o = reinterpret_cast<float4*>(h2out + (size_t)g * DH + sub * 8);
        h2o[0] = make_float4(h[0], h[1], h[2], h[3]);
        h2o[1] = make_float4(h[4], h[5], h[6], h[7]);
    }
    __syncthreads();

    float z[5];
#pragma unroll
    for (int q = 0; q < 5; ++q) z[q] = bc[sub * 5 + q];
#pragma unroll
    for (int k4 = 0; k4 < 8; ++k4) {
        float4 hv = *reinterpret_cast<const float4*>(&hs[n][k4 * 4]);   // ds_read_b128
        float hk[4] = {hv.x, hv.y, hv.z, hv.w};
#pragma unroll
        for (int kk = 0; kk < 4; ++kk) {
            const float* wc = Wc + (k4*4+kk) * DOUT + sub * 5;
#pragma unroll
            for (int q = 0; q < 5; ++q) z[q] = fmaf(hk[kk], wc[q], z[q]);
        }
    }
    float m = z[0];
#pragma unroll
    for (int q = 1; q < 5; ++q) m = fmaxf(m, z[q]);
    m = fmaxf(m, __shfl_xor(m, 1));
    m = fmaxf(m, __shfl_xor(m, 2));
    float s = 0.f;
#pragma unroll
    for (int q = 0; q < 5; ++q) s += expf(z[q] - m);
    s += __shfl_xor(s, 1);
    s += __shfl_xor(s, 2);
    float lse = m + logf(s);
    if (valid) {
        float* orow = outp + (size_t)g * DOUT + sub * 5;
#pragma unroll
        for (int q = 0; q < 5; ++q) orow[q] = z[q] - lse;
    }
}

extern "C" void kernel_launch(void* const* d_in, const int* in_sizes, int n_in,
                              void* d_out, int out_size, void* d_ws, size_t ws_size,
                              hipStream_t stream) {
    const float* x   = (const float*)d_in[0];
    const int*   ei  = (const int*)d_in[1];
    const float* W1l = (const float*)d_in[2];
    const float* b1  = (const float*)d_in[3];
    const float* W1r = (const float*)d_in[4];
    const float* W2l = (const float*)d_in[5];
    const float* b2  = (const float*)d_in[6];
    const float* W2r = (const float*)d_in[7];
    const float* Wc  = (const float*)d_in[8];
    const float* bc  = (const float*)d_in[9];

    float* outp = (float*)d_out;                          // [NN, 20]
    float* hout = outp + (size_t)NN * DOUT;               // [NN, 32]

    // workspace layout (fp8 feature table: 3.2 MB, L2-resident per XCD)
    unsigned char* xlf8 = (unsigned char*)d_ws;           // NN*DH fp8 (3.2 MB)
    float* xr      = (float*)(xlf8 + (size_t)NN * DH);    // NN*DH f32 (also hr)
    float* agg     = xr + (size_t)NN * DH;                // NN*DH f32 (aliases csrtmp)
    unsigned* csrtmp = (unsigned*)agg;                    // NE u32
    int* csrsrc    = (int*)(agg + (size_t)NN * DH);       // NE
    int* deg       = csrsrc + NE;                         // NN
    int* start     = deg + NN;                            // NN
    int* counts    = start + NN;                          // NBLK*NB
    int* offs      = counts + NBLK * NB;                  // NB*NBLK
    int* totals    = offs + NB * NBLK;                    // NB
    int* bases     = totals + NB;                         // NB+1

    const int lin1Blocks   = (NN + NPB - 1) / NPB;        // 1563
    const int postBlocks   = (NN + PPB - 1) / PPB;        // 1563
    const int gatherBlocks = (NN * 8 + 255) / 256;        // 3125

    lin1_kernel<<<lin1Blocks, 256, 0, stream>>>(x, W1l, W1r, xlf8, xr);

    countA_kernel<<<NBLK, 1024, 0, stream>>>(ei, counts);
    scanB1_kernel<<<NB, 256, 0, stream>>>(counts, offs, totals);
    scanB2_kernel<<<1, 64, 0, stream>>>(totals, bases);
    scatterC_kernel<<<NBLK, 1024, 0, stream>>>(ei, offs, bases, csrtmp);
    regroupD_kernel<<<NBUSE, 1024, 0, stream>>>(csrtmp, bases, csrsrc, deg, start);

    gather_kernel<<<gatherBlocks, 256, 0, stream>>>(start, deg, csrsrc,
                                                    (const unsigned*)xlf8, agg);
    post1_kernel<<<postBlocks, 256, 0, stream>>>(agg, deg, xr, b1, W2l, W2r, xlf8, xr);

    gather_kernel<<<gatherBlocks, 256, 0, stream>>>(start, deg, csrsrc,
                                                    (const unsigned*)xlf8, agg);
    post2_kernel<<<postBlocks, 256, 0, stream>>>(agg, deg, xr, b2, Wc, bc, hout, outp);
}

// Round 19
// 188.186 us; speedup vs baseline: 1.1307x; 1.0129x over previous
//
#include <hip/hip_runtime.h>
#include <hip/hip_fp16.h>
#include <cmath>

constexpr int NN   = 100000;
constexpr int NE   = 3200000;
constexpr int DIN  = 128;
constexpr int DH   = 32;
constexpr int DOUT = 20;

constexpr int NB    = 392;                 // coarse buckets: dst>>8 -> 0..390 (+1 pad)
constexpr int NBUSE = (NN + 255) / 256;    // 391 buckets actually used
constexpr int NBLK  = 256;                 // phase A/C blocks
constexpr int SLICE = NE / NBLK;           // 12500 edges per block (exact)

constexpr int NPB = 64;                    // nodes per lin1 block
constexpr int XSB = 136;                   // bf16 LDS row stride (16B-aligned, 2-way banks)
constexpr int PPB = 64;                    // nodes per post block (4 lanes/node)
constexpr int HSS = 36;                    // post hs row stride (16B-aligned, 2-way banks)

typedef __attribute__((ext_vector_type(8))) short short8v;   // 8 bf16 (4 VGPRs)
typedef __attribute__((ext_vector_type(4))) float f32x4;     // MFMA accumulator

__device__ inline unsigned short f2bf(float f) {           // RNE float->bf16
    unsigned u = __builtin_bit_cast(unsigned, f);
    unsigned r = 0x7FFFu + ((u >> 16) & 1u);
    return (unsigned short)((u + r) >> 16);
}

// ---- manual fp8 e4m3fn codec (extended-low: e=0 decodes as 2^-7*(1+m/8)) ----
__device__ inline unsigned f2fp8(float f) {                // RNE float->fp8 byte
    unsigned u = __builtin_bit_cast(unsigned, f);
    unsigned s = (u >> 24) & 0x80u;
    unsigned au = u & 0x7fffffffu;
    if (au > 0x43E00000u) au = 0x43E00000u;                // clamp to 448
    unsigned u2 = au + 0x7FFFFu + ((au >> 20) & 1u);       // RNE on dropped 20 bits
    int em = (int)(u2 >> 20) - (120 << 3);                 // (E-120)<<3 | m
    em = em < 0 ? 0 : (em > 0x7E ? 0x7E : em);
    return s | (unsigned)em;
}
__device__ inline float dec8(unsigned b) {                 // fp8 byte -> float
    unsigned r = ((b & 0x80u) << 24) | (((b & 0x7fu) << 20) + 0x3C000000u);
    return __builtin_bit_cast(float, r);
}

// ------------- layer-1 projections via MFMA: xl(fp8)=x@W1l, xr(f32)=x@W1r -------------
__global__ __launch_bounds__(256, 4) void lin1_kernel(
    const float* __restrict__ x, const float* __restrict__ Wl,
    const float* __restrict__ Wr, unsigned char* __restrict__ xlf8,
    float* __restrict__ xr)
{
    __shared__ unsigned short xs[NPB * XSB];   // 17408 B
    int t = threadIdx.x;
    int nodeBase = blockIdx.x * NPB;

    const float4* x4 = reinterpret_cast<const float4*>(x) + (size_t)nodeBase * (DIN / 4);
    for (int i = t; i < NPB * (DIN / 4); i += 256) {
        int n = i >> 5, c = i & 31;
        float4 v = make_float4(0.f, 0.f, 0.f, 0.f);
        if (nodeBase + n < NN) v = x4[i];
        unsigned lo = (unsigned)f2bf(v.x) | ((unsigned)f2bf(v.y) << 16);
        unsigned hi = (unsigned)f2bf(v.z) | ((unsigned)f2bf(v.w) << 16);
        *reinterpret_cast<uint2*>(&xs[n * XSB + c * 4]) = make_uint2(lo, hi);
    }
    __syncthreads();

    int wv   = t >> 6;                 // 0..3
    int lane = t & 63;
    const float* W = (wv & 2) ? Wr : Wl;
    int jbase = (wv & 1) * 16;
    int ncol  = jbase + (lane & 15);   // B: col = lane&15
    int krow  = (lane >> 4) * 8;       // B/A: k-chunk = (lane>>4)*8

    short8v bfrag[4];
#pragma unroll
    for (int ks = 0; ks < 4; ++ks) {
        const float* wp = W + (ks * 32 + krow) * DH + ncol;
        short8v f;
#pragma unroll
        for (int e = 0; e < 8; ++e) f[e] = (short)f2bf(wp[e * DH]);
        bfrag[ks] = f;
    }

    f32x4 acc[4];
#pragma unroll
    for (int m = 0; m < 4; ++m) acc[m] = f32x4{0.f, 0.f, 0.f, 0.f};

#pragma unroll
    for (int m = 0; m < 4; ++m) {
        int row = m * 16 + (lane & 15);
#pragma unroll
        for (int ks = 0; ks < 4; ++ks) {
            short8v a = *reinterpret_cast<const short8v*>(&xs[row * XSB + ks * 32 + krow]);
            acc[m] = __builtin_amdgcn_mfma_f32_16x16x32_bf16(a, bfrag[ks], acc[m], 0, 0, 0);
        }
    }

#pragma unroll
    for (int m = 0; m < 4; ++m) {
        int rbase = m * 16 + (lane >> 4) * 4;
#pragma unroll
        for (int r = 0; r < 4; ++r) {
            int node = nodeBase + rbase + r;
            if (node < NN) {
                float v = acc[m][r];
                if (wv & 2) xr[(size_t)node * DH + ncol] = v;
                else        xlf8[(size_t)node * DH + ncol] = (unsigned char)f2fp8(v);
            }
        }
    }
}

// ---------------- phase A: per-block coarse-bucket histogram (1024 thr) ----------------
__global__ __launch_bounds__(1024) void countA_kernel(
    const int* __restrict__ ei, int* __restrict__ counts)
{
    __shared__ int h[NB];
    int blk = blockIdx.x, t = threadIdx.x;
    for (int i = t; i < NB; i += 1024) h[i] = 0;
    __syncthreads();
    int base = blk * SLICE;
    for (int i = base + t; i < base + SLICE; i += 1024) {
        int dst = ei[NE + i];
        atomicAdd(&h[dst >> 8], 1);
    }
    __syncthreads();
    for (int i = t; i < NB; i += 1024) counts[blk * NB + i] = h[i];
}

// ------- phase B1: per-bucket exclusive scan, XCD-GROUPED segment order -------
// Segments within a bucket are laid out in rank order tp=(blk&7)*32+(blk>>3)
// so adjacent segments belong to same-XCD blocks -> boundary cache lines
// write-combine in one XCD's L2 instead of bouncing between XCDs.
__global__ __launch_bounds__(256) void scanB1_kernel(
    const int* __restrict__ counts, int* __restrict__ offs, int* __restrict__ totals)
{
    __shared__ int sdata[256];
    int b = blockIdx.x, t = threadIdx.x;
    int v = counts[t * NB + b];
    int tp = (t & 7) * 32 + (t >> 3);      // XCD-grouped rank of block t
    sdata[tp] = v;
    __syncthreads();
    for (int off = 1; off < 256; off <<= 1) {
        int tmp = (t >= off) ? sdata[t - off] : 0;
        __syncthreads();
        sdata[t] += tmp;
        __syncthreads();
    }
    offs[b * 256 + t] = sdata[tp] - v;     // exclusive prefix at rank tp
    if (t == 255) totals[b] = sdata[255];
}

// ------- phase B2: exclusive scan of bucket totals (tiny) -------
__global__ void scanB2_kernel(const int* __restrict__ totals, int* __restrict__ bases)
{
    if (threadIdx.x == 0 && blockIdx.x == 0) {
        int acc = 0;
        for (int i = 0; i < NB; ++i) { bases[i] = acc; acc += totals[i]; }
        bases[NB] = acc;
    }
}

// ------- phase C: rank-based scatter into per-(block,bucket) regions (1024 thr) -------
__global__ __launch_bounds__(1024) void scatterC_kernel(
    const int* __restrict__ ei, const int* __restrict__ offs,
    const int* __restrict__ bases, unsigned* __restrict__ csrtmp)
{
    __shared__ int cnt[NB];
    __shared__ int wbase[NB];
    int blk = blockIdx.x, t = threadIdx.x;
    for (int i = t; i < NB; i += 1024) {
        cnt[i] = 0;
        wbase[i] = bases[i] + offs[i * 256 + blk];
    }
    __syncthreads();
    int base = blk * SLICE;
    for (int i = base + t; i < base + SLICE; i += 1024) {
        int dst = ei[NE + i];
        int src = ei[i];
        int b = dst >> 8;
        int r = atomicAdd(&cnt[b], 1);                       // LDS atomic
        csrtmp[wbase[b] + r] = ((unsigned)(dst & 255) << 17) | (unsigned)src;
    }
}

// ------- phase D: regroup within bucket -> final CSR + start + deg (1024 thr) -------
__global__ __launch_bounds__(1024) void regroupD_kernel(
    const unsigned* __restrict__ csrtmp, const int* __restrict__ bases,
    int* __restrict__ csrsrc, int* __restrict__ deg, int* __restrict__ start)
{
    __shared__ int h[256];
    __shared__ int sdata[256];
    int b = blockIdx.x, t = threadIdx.x;
    int lo = bases[b], hi = bases[b + 1];
    if (t < 256) h[t] = 0;
    __syncthreads();
    for (int i = lo + t; i < hi; i += 1024)
        atomicAdd(&h[csrtmp[i] >> 17], 1);
    __syncthreads();
    int v = 0;
    if (t < 256) { v = h[t]; sdata[t] = v; }
    __syncthreads();
    for (int off = 1; off < 256; off <<= 1) {
        int tmp = 0;
        if (t < 256 && t >= off) tmp = sdata[t - off];
        __syncthreads();
        if (t < 256) sdata[t] += tmp;
        __syncthreads();
    }
    if (t < 256) {
        int ex = sdata[t] - v;
        int node = b * 256 + t;
        if (node < NN) { start[node] = lo + ex; deg[node] = v; }
        h[t] = ex;
    }
    __syncthreads();
    for (int i = lo + t; i < hi; i += 1024) {
        unsigned u = csrtmp[i];
        int r = atomicAdd(&h[u >> 17], 1);   // LDS atomic
        csrsrc[lo + r] = (int)(u & 0x1FFFFu);
    }
}

// ------- gather (fp8 rows, 32 B/row): packed-f16 accumulate, 32-bit addressing -------
__global__ __launch_bounds__(256) void gather_kernel(
    const int* __restrict__ start, const int* __restrict__ deg,
    const int* __restrict__ csrsrc, const unsigned* __restrict__ feat8,
    float* __restrict__ agg)
{
    int tid = blockIdx.x * 256 + threadIdx.x;
    int g = tid >> 3;            // node
    unsigned c = tid & 7;        // uint chunk (4 fp8) of the 32-dim row
    if (g >= NN) return;
    int s = start[g];
    int e = s + deg[g];
    __half2 zero2 = __float2half2_rn(0.f);
    __half2 p0a = zero2, p0b = zero2, p1a = zero2, p1b = zero2;
    __half2 p2a = zero2, p2b = zero2, p3a = zero2, p3b = zero2;
    int i = s;
    for (; i + 8 <= e; i += 8) {
        unsigned off[8];
#pragma unroll
        for (int q = 0; q < 8; ++q) off[q] = (unsigned)csrsrc[i + q] * 8u + c;
        unsigned vv[8];
#pragma unroll
        for (int q = 0; q < 8; ++q) vv[q] = feat8[off[q]];
#pragma unroll
        for (int q = 0; q < 8; ++q) {
            unsigned w = vv[q];
            unsigned p01 = __builtin_amdgcn_perm(0u, w, 0x04010400u); // 0x00b1_00b0
            unsigned p23 = __builtin_amdgcn_perm(0u, w, 0x04030402u); // 0x00b3_00b2
            unsigned h01 = ((p01 & 0x00800080u) << 8) |
                           (((p01 << 7) & 0x3F803F80u) + 0x20002000u); // fp8->f16 exact
            unsigned h23 = ((p23 & 0x00800080u) << 8) |
                           (((p23 << 7) & 0x3F803F80u) + 0x20002000u);
            __half2 a01 = __builtin_bit_cast(__half2, h01);
            __half2 a23 = __builtin_bit_cast(__half2, h23);
            if ((q & 3) == 0) { p0a = __hadd2(p0a, a01); p0b = __hadd2(p0b, a23); }
            if ((q & 3) == 1) { p1a = __hadd2(p1a, a01); p1b = __hadd2(p1b, a23); }
            if ((q & 3) == 2) { p2a = __hadd2(p2a, a01); p2b = __hadd2(p2b, a23); }
            if ((q & 3) == 3) { p3a = __hadd2(p3a, a01); p3b = __hadd2(p3b, a23); }
        }
    }
    float4 tl = make_float4(0.f, 0.f, 0.f, 0.f);
    for (; i < e; ++i) {
        unsigned w = feat8[(unsigned)csrsrc[i] * 8u + c];
        tl.x += dec8(w & 0xFFu);         tl.y += dec8((w >> 8) & 0xFFu);
        tl.z += dec8((w >> 16) & 0xFFu); tl.w += dec8(w >> 24);
    }
    float2 f0a = __half22float2(p0a), f1a = __half22float2(p1a);
    float2 f2a = __half22float2(p2a), f3a = __half22float2(p3a);
    float2 f0b = __half22float2(p0b), f1b = __half22float2(p1b);
    float2 f2b = __half22float2(p2b), f3b = __half22float2(p3b);
    float4 r;
    r.x = tl.x + f0a.x + f1a.x + f2a.x + f3a.x;
    r.y = tl.y + f0a.y + f1a.y + f2a.y + f3a.y;
    r.z = tl.z + f0b.x + f1b.x + f2b.x + f3b.x;
    r.w = tl.w + f0b.y + f1b.y + f2b.y + f3b.y;
    reinterpret_cast<float4*>(agg)[(size_t)g * 8 + c] = r;
}

// ---- post layer1 (4 lanes/node): o = agg/deg + b1 + xr; h1 = tanh(l2norm(o));
//      hl(fp8) = h1@W2l, hr(f32) = h1@W2r  — split k-loops, aligned hs ----
__global__ __launch_bounds__(256) void post1_kernel(
    const float* __restrict__ agg, const int* __restrict__ deg,
    const float* __restrict__ xr, const float* __restrict__ b1,
    const float* __restrict__ W2l, const float* __restrict__ W2r,
    unsigned char* __restrict__ hlf8, float* __restrict__ hr)
{
    __shared__ float hs[PPB][HSS];     // stride 36: 16B-aligned rows, 2-way banks
    int t = threadIdx.x;
    int n = t >> 2;                    // local node 0..63
    int sub = t & 3;                   // dim group: [sub*8, sub*8+8)
    int g = blockIdx.x * PPB + n;
    bool valid = g < NN;

    float o[8];
#pragma unroll
    for (int j = 0; j < 8; ++j) o[j] = 0.f;
    if (valid) {
        float inv = 1.0f / fmaxf((float)deg[g], 1.0f);
        const float4* ag4 = reinterpret_cast<const float4*>(agg + (size_t)g * DH + sub * 8);
        const float4* xr4 = reinterpret_cast<const float4*>(xr  + (size_t)g * DH + sub * 8);
        const float*  bp  = b1 + sub * 8;
#pragma unroll
        for (int q = 0; q < 2; ++q) {
            float4 a = ag4[q]; float4 r = xr4[q];
            o[q*4+0] = fmaf(a.x, inv, bp[q*4+0] + r.x);
            o[q*4+1] = fmaf(a.y, inv, bp[q*4+1] + r.y);
            o[q*4+2] = fmaf(a.z, inv, bp[q*4+2] + r.z);
            o[q*4+3] = fmaf(a.w, inv, bp[q*4+3] + r.w);
        }
    }
    float ss = 0.f;
#pragma unroll
    for (int j = 0; j < 8; ++j) ss += o[j] * o[j];
    ss += __shfl_xor(ss, 1);
    ss += __shfl_xor(ss, 2);
    float rn = 1.0f / fmaxf(sqrtf(ss), 1e-12f);
#pragma unroll
    for (int j = 0; j < 8; ++j) hs[n][sub * 8 + j] = tanhf(o[j] * rn);
    __syncthreads();

    // ---- loop A: al = h @ W2l (8 cols), fp8 encode + store ----
    float al[8];
#pragma unroll
    for (int j = 0; j < 8; ++j) al[j] = 0.f;
#pragma unroll
    for (int k4 = 0; k4 < 8; ++k4) {
        float4 hv = *reinterpret_cast<const float4*>(&hs[n][k4 * 4]);   // ds_read_b128
        float hk[4] = {hv.x, hv.y, hv.z, hv.w};
#pragma unroll
        for (int kk = 0; kk < 4; ++kk) {
            const float4* wl4 = reinterpret_cast<const float4*>(W2l + (k4*4+kk) * DH + sub * 8);
            float4 w0 = wl4[0], w1 = wl4[1];
            al[0] = fmaf(hk[kk], w0.x, al[0]);
            al[1] = fmaf(hk[kk], w0.y, al[1]);
            al[2] = fmaf(hk[kk], w0.z, al[2]);
            al[3] = fmaf(hk[kk], w0.w, al[3]);
            al[4] = fmaf(hk[kk], w1.x, al[4]);
            al[5] = fmaf(hk[kk], w1.y, al[5]);
            al[6] = fmaf(hk[kk], w1.z, al[6]);
            al[7] = fmaf(hk[kk], w1.w, al[7]);
        }
    }
    if (valid) {
        unsigned w0 = f2fp8(al[0]) | (f2fp8(al[1]) << 8) |
                      (f2fp8(al[2]) << 16) | (f2fp8(al[3]) << 24);
        unsigned w1 = f2fp8(al[4]) | (f2fp8(al[5]) << 8) |
                      (f2fp8(al[6]) << 16) | (f2fp8(al[7]) << 24);
        *reinterpret_cast<uint2*>(hlf8 + (size_t)g * DH + sub * 8) = make_uint2(w0, w1);
    }

    // ---- loop B: ar = h @ W2r (8 cols), f32 store ----
    float ar[8];
#pragma unroll
    for (int j = 0; j < 8; ++j) ar[j] = 0.f;
#pragma unroll
    for (int k4 = 0; k4 < 8; ++k4) {
        float4 hv = *reinterpret_cast<const float4*>(&hs[n][k4 * 4]);
        float hk[4] = {hv.x, hv.y, hv.z, hv.w};
#pragma unroll
        for (int kk = 0; kk < 4; ++kk) {
            const float4* wr4 = reinterpret_cast<const float4*>(W2r + (k4*4+kk) * DH + sub * 8);
            float4 w0 = wr4[0], w1 = wr4[1];
            ar[0] = fmaf(hk[kk], w0.x, ar[0]);
            ar[1] = fmaf(hk[kk], w0.y, ar[1]);
            ar[2] = fmaf(hk[kk], w0.z, ar[2]);
            ar[3] = fmaf(hk[kk], w0.w, ar[3]);
            ar[4] = fmaf(hk[kk], w1.x, ar[4]);
            ar[5] = fmaf(hk[kk], w1.y, ar[5]);
            ar[6] = fmaf(hk[kk], w1.z, ar[6]);
            ar[7] = fmaf(hk[kk], w1.w, ar[7]);
        }
    }
    if (valid) {
        float4* hr4 = reinterpret_cast<float4*>(hr + (size_t)g * DH + sub * 8);
        hr4[0] = make_float4(ar[0], ar[1], ar[2], ar[3]);
        hr4[1] = make_float4(ar[4], ar[5], ar[6], ar[7]);
    }
}

// ---- post layer2 + classifier (4 lanes/node), aligned hs ----
__global__ __launch_bounds__(256) void post2_kernel(
    const float* __restrict__ agg, const int* __restrict__ deg,
    const float* __restrict__ hr, const float* __restrict__ b2,
    const float* __restrict__ Wc, const float* __restrict__ bc,
    float* __restrict__ h2out, float* __restrict__ outp)
{
    __shared__ float hs[PPB][HSS];
    int t = threadIdx.x;
    int n = t >> 2;
    int sub = t & 3;
    int g = blockIdx.x * PPB + n;
    bool valid = g < NN;

    float o[8];
#pragma unroll
    for (int j = 0; j < 8; ++j) o[j] = 0.f;
    if (valid) {
        float inv = 1.0f / fmaxf((float)deg[g], 1.0f);
        const float4* ag4 = reinterpret_cast<const float4*>(agg + (size_t)g * DH + sub * 8);
        const float4* hr4 = reinterpret_cast<const float4*>(hr  + (size_t)g * DH + sub * 8);
        const float*  bp  = b2 + sub * 8;
#pragma unroll
        for (int q = 0; q < 2; ++q) {
            float4 a = ag4[q]; float4 r = hr4[q];
            o[q*4+0] = fmaf(a.x, inv, bp[q*4+0] + r.x);
            o[q*4+1] = fmaf(a.y, inv, bp[q*4+1] + r.y);
            o[q*4+2] = fmaf(a.z, inv, bp[q*4+2] + r.z);
            o[q*4+3] = fmaf(a.w, inv, bp[q*4+3] + r.w);
        }
    }
    float ss = 0.f;
#pragma unroll
    for (int j = 0; j < 8; ++j) ss += o[j] * o[j];
    ss += __shfl_xor(ss, 1);
    ss += __shfl_xor(ss, 2);
    float rn = 1.0f / fmaxf(sqrtf(ss), 1e-12f);
    float h[8];
#pragma unroll
    for (int j = 0; j < 8; ++j) h[j] = tanhf(o[j] * rn);
#pragma unroll
    for (int j = 0; j < 8; ++j) hs[n][sub * 8 + j] = h[j];
    if (valid) {
        float4* h2o = reinterpret_cast<float4*>(h2out + (size_t)g * DH + sub * 8);
        h2o[0] = make_float4(h[0], h[1], h[2], h[3]);
        h2o[1] = make_float4(h[4], h[5], h[6], h[7]);
    }
    __syncthreads();

    float z[5];
#pragma unroll
    for (int q = 0; q < 5; ++q) z[q] = bc[sub * 5 + q];
#pragma unroll
    for (int k4 = 0; k4 < 8; ++k4) {
        float4 hv = *reinterpret_cast<const float4*>(&hs[n][k4 * 4]);   // ds_read_b128
        float hk[4] = {hv.x, hv.y, hv.z, hv.w};
#pragma unroll
        for (int kk = 0; kk < 4; ++kk) {
            const float* wc = Wc + (k4*4+kk) * DOUT + sub * 5;
#pragma unroll
            for (int q = 0; q < 5; ++q) z[q] = fmaf(hk[kk], wc[q], z[q]);
        }
    }
    float m = z[0];
#pragma unroll
    for (int q = 1; q < 5; ++q) m = fmaxf(m, z[q]);
    m = fmaxf(m, __shfl_xor(m, 1));
    m = fmaxf(m, __shfl_xor(m, 2));
    float s = 0.f;
#pragma unroll
    for (int q = 0; q < 5; ++q) s += expf(z[q] - m);
    s += __shfl_xor(s, 1);
    s += __shfl_xor(s, 2);
    float lse = m + logf(s);
    if (valid) {
        float* orow = outp + (size_t)g * DOUT + sub * 5;
#pragma unroll
        for (int q = 0; q < 5; ++q) orow[q] = z[q] - lse;
    }
}

extern "C" void kernel_launch(void* const* d_in, const int* in_sizes, int n_in,
                              void* d_out, int out_size, void* d_ws, size_t ws_size,
                              hipStream_t stream) {
    const float* x   = (const float*)d_in[0];
    const int*   ei  = (const int*)d_in[1];
    const float* W1l = (const float*)d_in[2];
    const float* b1  = (const float*)d_in[3];
    const float* W1r = (const float*)d_in[4];
    const float* W2l = (const float*)d_in[5];
    const float* b2  = (const float*)d_in[6];
    const float* W2r = (const float*)d_in[7];
    const float* Wc  = (const float*)d_in[8];
    const float* bc  = (const float*)d_in[9];

    float* outp = (float*)d_out;                          // [NN, 20]
    float* hout = outp + (size_t)NN * DOUT;               // [NN, 32]

    // workspace layout (fp8 feature table: 3.2 MB, L2-resident per XCD)
    unsigned char* xlf8 = (unsigned char*)d_ws;           // NN*DH fp8 (3.2 MB)
    float* xr      = (float*)(xlf8 + (size_t)NN * DH);    // NN*DH f32 (also hr)
    float* agg     = xr + (size_t)NN * DH;                // NN*DH f32 (aliases csrtmp)
    unsigned* csrtmp = (unsigned*)agg;                    // NE u32
    int* csrsrc    = (int*)(agg + (size_t)NN * DH);       // NE
    int* deg       = csrsrc + NE;                         // NN
    int* start     = deg + NN;                            // NN
    int* counts    = start + NN;                          // NBLK*NB
    int* offs      = counts + NBLK * NB;                  // NB*NBLK
    int* totals    = offs + NB * NBLK;                    // NB
    int* bases     = totals + NB;                         // NB+1

    const int lin1Blocks   = (NN + NPB - 1) / NPB;        // 1563
    const int postBlocks   = (NN + PPB - 1) / PPB;        // 1563
    const int gatherBlocks = (NN * 8 + 255) / 256;        // 3125

    lin1_kernel<<<lin1Blocks, 256, 0, stream>>>(x, W1l, W1r, xlf8, xr);

    countA_kernel<<<NBLK, 1024, 0, stream>>>(ei, counts);
    scanB1_kernel<<<NB, 256, 0, stream>>>(counts, offs, totals);
    scanB2_kernel<<<1, 64, 0, stream>>>(totals, bases);
    scatterC_kernel<<<NBLK, 1024, 0, stream>>>(ei, offs, bases, csrtmp);
    regroupD_kernel<<<NBUSE, 1024, 0, stream>>>(csrtmp, bases, csrsrc, deg, start);

    gather_kernel<<<gatherBlocks, 256, 0, stream>>>(start, deg, csrsrc,
                                                    (const unsigned*)xlf8, agg);
    post1_kernel<<<postBlocks, 256, 0, stream>>>(agg, deg, xr, b1, W2l, W2r, xlf8, xr);

    gather_kernel<<<gatherBlocks, 256, 0, stream>>>(start, deg, csrsrc,
                                                    (const unsigned*)xlf8, agg);
    post2_kernel<<<postBlocks, 256, 0, stream>>>(agg, deg, xr, b2, Wc, bc, hout, outp);
}

// Round 20
// 181.351 us; speedup vs baseline: 1.1733x; 1.0377x over previous
//
#include <hip/hip_runtime.h>
#include <hip/hip_fp16.h>
#include <cmath>

constexpr int NN   = 100000;
constexpr int NE   = 3200000;
constexpr int DIN  = 128;
constexpr int DH   = 32;
constexpr int DOUT = 20;

constexpr int NB    = 392;                 // coarse buckets: dst>>8 -> 0..390 (+1 pad)
constexpr int NBUSE = (NN + 255) / 256;    // 391 buckets actually used
constexpr int NBLK  = 256;                 // phase A/C blocks
constexpr int SLICE = NE / NBLK;           // 12500 edges per block (exact)

constexpr int NPB = 64;                    // nodes per lin1 block
constexpr int XSB = 136;                   // bf16 LDS row stride (16B-aligned, 2-way banks)
constexpr int HSS = 36;                    // fused hs row stride (16B-aligned)

typedef __attribute__((ext_vector_type(8))) short short8v;   // 8 bf16 (4 VGPRs)
typedef __attribute__((ext_vector_type(4))) float f32x4;     // MFMA accumulator

__device__ inline unsigned short f2bf(float f) {           // RNE float->bf16
    unsigned u = __builtin_bit_cast(unsigned, f);
    unsigned r = 0x7FFFu + ((u >> 16) & 1u);
    return (unsigned short)((u + r) >> 16);
}

// ---- manual fp8 e4m3fn codec (extended-low: e=0 decodes as 2^-7*(1+m/8)) ----
__device__ inline unsigned f2fp8(float f) {                // RNE float->fp8 byte
    unsigned u = __builtin_bit_cast(unsigned, f);
    unsigned s = (u >> 24) & 0x80u;
    unsigned au = u & 0x7fffffffu;
    if (au > 0x43E00000u) au = 0x43E00000u;                // clamp to 448
    unsigned u2 = au + 0x7FFFFu + ((au >> 20) & 1u);       // RNE on dropped 20 bits
    int em = (int)(u2 >> 20) - (120 << 3);                 // (E-120)<<3 | m
    em = em < 0 ? 0 : (em > 0x7E ? 0x7E : em);
    return s | (unsigned)em;
}
__device__ inline float dec8(unsigned b) {                 // fp8 byte -> float
    unsigned r = ((b & 0x80u) << 24) | (((b & 0x7fu) << 20) + 0x3C000000u);
    return __builtin_bit_cast(float, r);
}

// ------------- layer-1 projections via MFMA: xl(fp8)=x@W1l, xr(f32)=x@W1r -------------
__global__ __launch_bounds__(256, 4) void lin1_kernel(
    const float* __restrict__ x, const float* __restrict__ Wl,
    const float* __restrict__ Wr, unsigned char* __restrict__ xlf8,
    float* __restrict__ xr)
{
    __shared__ unsigned short xs[NPB * XSB];   // 17408 B
    int t = threadIdx.x;
    int nodeBase = blockIdx.x * NPB;

    const float4* x4 = reinterpret_cast<const float4*>(x) + (size_t)nodeBase * (DIN / 4);
    for (int i = t; i < NPB * (DIN / 4); i += 256) {
        int n = i >> 5, c = i & 31;
        float4 v = make_float4(0.f, 0.f, 0.f, 0.f);
        if (nodeBase + n < NN) v = x4[i];
        unsigned lo = (unsigned)f2bf(v.x) | ((unsigned)f2bf(v.y) << 16);
        unsigned hi = (unsigned)f2bf(v.z) | ((unsigned)f2bf(v.w) << 16);
        *reinterpret_cast<uint2*>(&xs[n * XSB + c * 4]) = make_uint2(lo, hi);
    }
    __syncthreads();

    int wv   = t >> 6;                 // 0..3
    int lane = t & 63;
    const float* W = (wv & 2) ? Wr : Wl;
    int jbase = (wv & 1) * 16;
    int ncol  = jbase + (lane & 15);   // B: col = lane&15
    int krow  = (lane >> 4) * 8;       // B/A: k-chunk = (lane>>4)*8

    short8v bfrag[4];
#pragma unroll
    for (int ks = 0; ks < 4; ++ks) {
        const float* wp = W + (ks * 32 + krow) * DH + ncol;
        short8v f;
#pragma unroll
        for (int e = 0; e < 8; ++e) f[e] = (short)f2bf(wp[e * DH]);
        bfrag[ks] = f;
    }

    f32x4 acc[4];
#pragma unroll
    for (int m = 0; m < 4; ++m) acc[m] = f32x4{0.f, 0.f, 0.f, 0.f};

#pragma unroll
    for (int m = 0; m < 4; ++m) {
        int row = m * 16 + (lane & 15);
#pragma unroll
        for (int ks = 0; ks < 4; ++ks) {
            short8v a = *reinterpret_cast<const short8v*>(&xs[row * XSB + ks * 32 + krow]);
            acc[m] = __builtin_amdgcn_mfma_f32_16x16x32_bf16(a, bfrag[ks], acc[m], 0, 0, 0);
        }
    }

#pragma unroll
    for (int m = 0; m < 4; ++m) {
        int rbase = m * 16 + (lane >> 4) * 4;
#pragma unroll
        for (int r = 0; r < 4; ++r) {
            int node = nodeBase + rbase + r;
            if (node < NN) {
                float v = acc[m][r];
                if (wv & 2) xr[(size_t)node * DH + ncol] = v;
                else        xlf8[(size_t)node * DH + ncol] = (unsigned char)f2fp8(v);
            }
        }
    }
}

// ---------------- phase A: per-block coarse-bucket histogram (1024 thr) ----------------
__global__ __launch_bounds__(1024) void countA_kernel(
    const int* __restrict__ ei, int* __restrict__ counts)
{
    __shared__ int h[NB];
    int blk = blockIdx.x, t = threadIdx.x;
    for (int i = t; i < NB; i += 1024) h[i] = 0;
    __syncthreads();
    int base = blk * SLICE;
    for (int i = base + t; i < base + SLICE; i += 1024) {
        int dst = ei[NE + i];
        atomicAdd(&h[dst >> 8], 1);
    }
    __syncthreads();
    for (int i = t; i < NB; i += 1024) counts[blk * NB + i] = h[i];
}

// ------- phase B1: per-bucket exclusive scan, XCD-GROUPED segment order -------
__global__ __launch_bounds__(256) void scanB1_kernel(
    const int* __restrict__ counts, int* __restrict__ offs, int* __restrict__ totals)
{
    __shared__ int sdata[256];
    int b = blockIdx.x, t = threadIdx.x;
    int v = counts[t * NB + b];
    int tp = (t & 7) * 32 + (t >> 3);      // XCD-grouped rank of block t
    sdata[tp] = v;
    __syncthreads();
    for (int off = 1; off < 256; off <<= 1) {
        int tmp = (t >= off) ? sdata[t - off] : 0;
        __syncthreads();
        sdata[t] += tmp;
        __syncthreads();
    }
    offs[b * 256 + t] = sdata[tp] - v;     // exclusive prefix at rank tp
    if (t == 255) totals[b] = sdata[255];
}

// ------- phase B2: exclusive scan of bucket totals + start sentinel -------
__global__ void scanB2_kernel(const int* __restrict__ totals, int* __restrict__ bases,
                              int* __restrict__ start)
{
    if (threadIdx.x == 0 && blockIdx.x == 0) {
        int acc = 0;
        for (int i = 0; i < NB; ++i) { bases[i] = acc; acc += totals[i]; }
        bases[NB] = acc;
        start[NN] = acc;                   // sentinel: deg[g] = start[g+1]-start[g]
    }
}

// ------- phase C: rank-based scatter into per-(block,bucket) regions (1024 thr) -------
__global__ __launch_bounds__(1024) void scatterC_kernel(
    const int* __restrict__ ei, const int* __restrict__ offs,
    const int* __restrict__ bases, unsigned* __restrict__ csrtmp)
{
    __shared__ int cnt[NB];
    __shared__ int wbase[NB];
    int blk = blockIdx.x, t = threadIdx.x;
    for (int i = t; i < NB; i += 1024) {
        cnt[i] = 0;
        wbase[i] = bases[i] + offs[i * 256 + blk];
    }
    __syncthreads();
    int base = blk * SLICE;
    for (int i = base + t; i < base + SLICE; i += 1024) {
        int dst = ei[NE + i];
        int src = ei[i];
        int b = dst >> 8;
        int r = atomicAdd(&cnt[b], 1);                       // LDS atomic
        csrtmp[wbase[b] + r] = ((unsigned)(dst & 255) << 17) | (unsigned)src;
    }
}

// ------- phase D: regroup within bucket -> final CSR + start (1024 thr) -------
__global__ __launch_bounds__(1024) void regroupD_kernel(
    const unsigned* __restrict__ csrtmp, const int* __restrict__ bases,
    int* __restrict__ csrsrc, int* __restrict__ start)
{
    __shared__ int h[256];
    __shared__ int sdata[256];
    int b = blockIdx.x, t = threadIdx.x;
    int lo = bases[b], hi = bases[b + 1];
    if (t < 256) h[t] = 0;
    __syncthreads();
    for (int i = lo + t; i < hi; i += 1024)
        atomicAdd(&h[csrtmp[i] >> 17], 1);
    __syncthreads();
    int v = 0;
    if (t < 256) { v = h[t]; sdata[t] = v; }
    __syncthreads();
    for (int off = 1; off < 256; off <<= 1) {
        int tmp = 0;
        if (t < 256 && t >= off) tmp = sdata[t - off];
        __syncthreads();
        if (t < 256) sdata[t] += tmp;
        __syncthreads();
    }
    if (t < 256) {
        int ex = sdata[t] - v;
        int node = b * 256 + t;
        if (node < NN) start[node] = lo + ex;
        h[t] = ex;
    }
    __syncthreads();
    for (int i = lo + t; i < hi; i += 1024) {
        unsigned u = csrtmp[i];
        int r = atomicAdd(&h[u >> 17], 1);   // LDS atomic
        csrsrc[lo + r] = (int)(u & 0x1FFFFu);
    }
}

// ===== shared gather core: 8 lanes/node, fp8 rows, packed-f16 accumulate =====
__device__ inline float4 gather_core(const int* __restrict__ csrsrc,
                                     const unsigned* __restrict__ feat8,
                                     int s, int e, unsigned c)
{
    __half2 zero2 = __float2half2_rn(0.f);
    __half2 p0a = zero2, p0b = zero2, p1a = zero2, p1b = zero2;
    __half2 p2a = zero2, p2b = zero2, p3a = zero2, p3b = zero2;
    int i = s;
    for (; i + 8 <= e; i += 8) {
        unsigned off[8];
#pragma unroll
        for (int q = 0; q < 8; ++q) off[q] = (unsigned)csrsrc[i + q] * 8u + c;
        unsigned vv[8];
#pragma unroll
        for (int q = 0; q < 8; ++q) vv[q] = feat8[off[q]];
#pragma unroll
        for (int q = 0; q < 8; ++q) {
            unsigned w = vv[q];
            unsigned p01 = __builtin_amdgcn_perm(0u, w, 0x04010400u);
            unsigned p23 = __builtin_amdgcn_perm(0u, w, 0x04030402u);
            unsigned h01 = ((p01 & 0x00800080u) << 8) |
                           (((p01 << 7) & 0x3F803F80u) + 0x20002000u);
            unsigned h23 = ((p23 & 0x00800080u) << 8) |
                           (((p23 << 7) & 0x3F803F80u) + 0x20002000u);
            __half2 a01 = __builtin_bit_cast(__half2, h01);
            __half2 a23 = __builtin_bit_cast(__half2, h23);
            if ((q & 3) == 0) { p0a = __hadd2(p0a, a01); p0b = __hadd2(p0b, a23); }
            if ((q & 3) == 1) { p1a = __hadd2(p1a, a01); p1b = __hadd2(p1b, a23); }
            if ((q & 3) == 2) { p2a = __hadd2(p2a, a01); p2b = __hadd2(p2b, a23); }
            if ((q & 3) == 3) { p3a = __hadd2(p3a, a01); p3b = __hadd2(p3b, a23); }
        }
    }
    float4 tl = make_float4(0.f, 0.f, 0.f, 0.f);
    for (; i < e; ++i) {
        unsigned w = feat8[(unsigned)csrsrc[i] * 8u + c];
        tl.x += dec8(w & 0xFFu);         tl.y += dec8((w >> 8) & 0xFFu);
        tl.z += dec8((w >> 16) & 0xFFu); tl.w += dec8(w >> 24);
    }
    float2 f0a = __half22float2(p0a), f1a = __half22float2(p1a);
    float2 f2a = __half22float2(p2a), f3a = __half22float2(p3a);
    float2 f0b = __half22float2(p0b), f1b = __half22float2(p1b);
    float2 f2b = __half22float2(p2b), f3b = __half22float2(p3b);
    float4 r;
    r.x = tl.x + f0a.x + f1a.x + f2a.x + f3a.x;
    r.y = tl.y + f0a.y + f1a.y + f2a.y + f3a.y;
    r.z = tl.z + f0b.x + f1b.x + f2b.x + f3b.x;
    r.w = tl.w + f0b.y + f1b.y + f2b.y + f3b.y;
    return r;
}

// ===== fused layer 1: gather(xlf8) + mean + b1 + xr + l2norm + tanh
//       + hl(fp8)=h@W2l -> hlf8, hr(f32)=h@W2r -> hr (aliases xr, node-local) =====
__global__ __launch_bounds__(256) void fused1_kernel(
    const int* __restrict__ start, const int* __restrict__ csrsrc,
    const unsigned* __restrict__ feat8, const float* __restrict__ xr,
    const float* __restrict__ b1, const float* __restrict__ W2l,
    const float* __restrict__ W2r, unsigned* __restrict__ hlf8u,
    float* __restrict__ hr)
{
    __shared__ float hs[32][HSS];
    int tid = blockIdx.x * 256 + threadIdx.x;   // grid exact: NN*8 threads
    int g = tid >> 3;
    unsigned c = threadIdx.x & 7;
    int nl = threadIdx.x >> 3;                  // 0..31

    int s = start[g];
    int e = start[g + 1];
    float4 r = gather_core(csrsrc, feat8, s, e, c);

    float inv = 1.0f / fmaxf((float)(e - s), 1.0f);
    const float4 root = *reinterpret_cast<const float4*>(xr + (size_t)g * DH + c * 4);
    const float4 bb   = *reinterpret_cast<const float4*>(b1 + c * 4);
    float4 o;
    o.x = fmaf(r.x, inv, bb.x + root.x);
    o.y = fmaf(r.y, inv, bb.y + root.y);
    o.z = fmaf(r.z, inv, bb.z + root.z);
    o.w = fmaf(r.w, inv, bb.w + root.w);

    float ss = o.x*o.x + o.y*o.y + o.z*o.z + o.w*o.w;
    ss += __shfl_xor(ss, 1);
    ss += __shfl_xor(ss, 2);
    ss += __shfl_xor(ss, 4);
    float rn = 1.0f / fmaxf(sqrtf(ss), 1e-12f);
    float4 h;
    h.x = tanhf(o.x * rn); h.y = tanhf(o.y * rn);
    h.z = tanhf(o.z * rn); h.w = tanhf(o.w * rn);
    *reinterpret_cast<float4*>(&hs[nl][c * 4]) = h;
    __syncthreads();

    float al[4] = {0.f, 0.f, 0.f, 0.f};
    float ar[4] = {0.f, 0.f, 0.f, 0.f};
#pragma unroll
    for (int k4 = 0; k4 < 8; ++k4) {
        float4 hv = *reinterpret_cast<const float4*>(&hs[nl][k4 * 4]);
        float hk[4] = {hv.x, hv.y, hv.z, hv.w};
#pragma unroll
        for (int kk = 0; kk < 4; ++kk) {
            const float4* wl4 = reinterpret_cast<const float4*>(W2l + (k4*4+kk) * DH + c * 4);
            const float4* wr4 = reinterpret_cast<const float4*>(W2r + (k4*4+kk) * DH + c * 4);
            float4 wl = wl4[0], wr = wr4[0];
            al[0] = fmaf(hk[kk], wl.x, al[0]);
            al[1] = fmaf(hk[kk], wl.y, al[1]);
            al[2] = fmaf(hk[kk], wl.z, al[2]);
            al[3] = fmaf(hk[kk], wl.w, al[3]);
            ar[0] = fmaf(hk[kk], wr.x, ar[0]);
            ar[1] = fmaf(hk[kk], wr.y, ar[1]);
            ar[2] = fmaf(hk[kk], wr.z, ar[2]);
            ar[3] = fmaf(hk[kk], wr.w, ar[3]);
        }
    }
    hlf8u[(size_t)g * 8 + c] = f2fp8(al[0]) | (f2fp8(al[1]) << 8) |
                               (f2fp8(al[2]) << 16) | (f2fp8(al[3]) << 24);
    *reinterpret_cast<float4*>(hr + (size_t)g * DH + c * 4) =
        make_float4(ar[0], ar[1], ar[2], ar[3]);
}

// ===== fused layer 2: gather(hlf8) + mean + b2 + hr + l2norm + tanh
//       + h2 -> hout, log_softmax(h2@Wc + bc) -> outp =====
__global__ __launch_bounds__(256) void fused2_kernel(
    const int* __restrict__ start, const int* __restrict__ csrsrc,
    const unsigned* __restrict__ feat8, const float* __restrict__ hr,
    const float* __restrict__ b2, const float* __restrict__ Wc,
    const float* __restrict__ bc, float* __restrict__ h2out,
    float* __restrict__ outp)
{
    __shared__ float hs[32][HSS];
    int tid = blockIdx.x * 256 + threadIdx.x;
    int g = tid >> 3;
    unsigned c = threadIdx.x & 7;
    int nl = threadIdx.x >> 3;

    int s = start[g];
    int e = start[g + 1];
    float4 r = gather_core(csrsrc, feat8, s, e, c);

    float inv = 1.0f / fmaxf((float)(e - s), 1.0f);
    const float4 root = *reinterpret_cast<const float4*>(hr + (size_t)g * DH + c * 4);
    const float4 bb   = *reinterpret_cast<const float4*>(b2 + c * 4);
    float4 o;
    o.x = fmaf(r.x, inv, bb.x + root.x);
    o.y = fmaf(r.y, inv, bb.y + root.y);
    o.z = fmaf(r.z, inv, bb.z + root.z);
    o.w = fmaf(r.w, inv, bb.w + root.w);

    float ss = o.x*o.x + o.y*o.y + o.z*o.z + o.w*o.w;
    ss += __shfl_xor(ss, 1);
    ss += __shfl_xor(ss, 2);
    ss += __shfl_xor(ss, 4);
    float rn = 1.0f / fmaxf(sqrtf(ss), 1e-12f);
    float4 h;
    h.x = tanhf(o.x * rn); h.y = tanhf(o.y * rn);
    h.z = tanhf(o.z * rn); h.w = tanhf(o.w * rn);
    *reinterpret_cast<float4*>(&hs[nl][c * 4]) = h;
    *reinterpret_cast<float4*>(h2out + (size_t)g * DH + c * 4) = h;
    __syncthreads();

    // classifier: lanes 0-3 of each 8-lane group compute 5 logits each
    if (c < 4) {
        float z[5];
#pragma unroll
        for (int q = 0; q < 5; ++q) z[q] = bc[c * 5 + q];
#pragma unroll
        for (int k4 = 0; k4 < 8; ++k4) {
            float4 hv = *reinterpret_cast<const float4*>(&hs[nl][k4 * 4]);
            float hk[4] = {hv.x, hv.y, hv.z, hv.w};
#pragma unroll
            for (int kk = 0; kk < 4; ++kk) {
                const float* wc = Wc + (k4*4+kk) * DOUT + c * 5;
#pragma unroll
                for (int q = 0; q < 5; ++q) z[q] = fmaf(hk[kk], wc[q], z[q]);
            }
        }
        float m = z[0];
#pragma unroll
        for (int q = 1; q < 5; ++q) m = fmaxf(m, z[q]);
        m = fmaxf(m, __shfl_xor(m, 1));
        m = fmaxf(m, __shfl_xor(m, 2));
        float sum = 0.f;
#pragma unroll
        for (int q = 0; q < 5; ++q) sum += expf(z[q] - m);
        sum += __shfl_xor(sum, 1);
        sum += __shfl_xor(sum, 2);
        float lse = m + logf(sum);
        float* orow = outp + (size_t)g * DOUT + c * 5;
#pragma unroll
        for (int q = 0; q < 5; ++q) orow[q] = z[q] - lse;
    }
}

extern "C" void kernel_launch(void* const* d_in, const int* in_sizes, int n_in,
                              void* d_out, int out_size, void* d_ws, size_t ws_size,
                              hipStream_t stream) {
    const float* x   = (const float*)d_in[0];
    const int*   ei  = (const int*)d_in[1];
    const float* W1l = (const float*)d_in[2];
    const float* b1  = (const float*)d_in[3];
    const float* W1r = (const float*)d_in[4];
    const float* W2l = (const float*)d_in[5];
    const float* b2  = (const float*)d_in[6];
    const float* W2r = (const float*)d_in[7];
    const float* Wc  = (const float*)d_in[8];
    const float* bc  = (const float*)d_in[9];

    float* outp = (float*)d_out;                          // [NN, 20]
    float* hout = outp + (size_t)NN * DOUT;               // [NN, 32]

    // workspace layout
    unsigned char* xlf8 = (unsigned char*)d_ws;           // NN*DH fp8 (3.2 MB)
    unsigned char* hlf8 = xlf8 + (size_t)NN * DH;         // NN*DH fp8 (3.2 MB)
    float* xr      = (float*)(hlf8 + (size_t)NN * DH);    // NN*DH f32 (also hr, node-local)
    unsigned* csrtmp = (unsigned*)(xr + (size_t)NN * DH); // NE u32
    int* csrsrc    = (int*)(csrtmp + NE);                 // NE
    int* start     = csrsrc + NE;                         // NN+1 (sentinel)
    int* counts    = start + NN + 1;                      // NBLK*NB
    int* offs      = counts + NBLK * NB;                  // NB*NBLK
    int* totals    = offs + NB * NBLK;                    // NB
    int* bases     = totals + NB;                         // NB+1

    const int lin1Blocks  = (NN + NPB - 1) / NPB;         // 1563
    const int fusedBlocks = (NN * 8) / 256;               // 3125 exact

    lin1_kernel<<<lin1Blocks, 256, 0, stream>>>(x, W1l, W1r, xlf8, xr);

    countA_kernel<<<NBLK, 1024, 0, stream>>>(ei, counts);
    scanB1_kernel<<<NB, 256, 0, stream>>>(counts, offs, totals);
    scanB2_kernel<<<1, 64, 0, stream>>>(totals, bases, start);
    scatterC_kernel<<<NBLK, 1024, 0, stream>>>(ei, offs, bases, csrtmp);
    regroupD_kernel<<<NBUSE, 1024, 0, stream>>>(csrtmp, bases, csrsrc, start);

    fused1_kernel<<<fusedBlocks, 256, 0, stream>>>(start, csrsrc,
        (const unsigned*)xlf8, xr, b1, W2l, W2r, (unsigned*)hlf8, xr);

    fused2_kernel<<<fusedBlocks, 256, 0, stream>>>(start, csrsrc,
        (const unsigned*)hlf8, xr, b2, Wc, bc, hout, outp);
}